// Round 9
// baseline (595.179 us; speedup 1.0000x reference)
//
#include <hip/hip_runtime.h>
#include <math.h>

// ---------------------------------------------------------------- constants
#define BB 8
#define TT 2048
#define DV_ 1024
#define DA_ 128
#define D1_ 512
#define D2_ 128
#define DH_ 257
#define DHP 288            // padded (zeros): divisible by 32 for MFMA K-chunks
#define DG_ 128
#define MTOT (BB*TT)       // 16384 rows
#define NPX ((size_t)MTOT*DHP)

#define NEGS 0.01f
#define INV_E 0.36787944117144233f
#define CH 64              // scan chunk rows
#define HALO 128           // r^128 ~ 3.5e-21: carry beyond halo is sub-eps

// ---------------------------------------------------------------- workspace
static const size_t o_big = 0;                     // 16,777,216 f
static const size_t o_c1  = 16777216;              //  8,388,608 f
static const size_t o_c2  = o_c1 + 8388608;        //  2,097,152 f
static const size_t o_w   = o_c2 + 2097152;        //    663,552 f (split weights)
static const size_t o_S   = o_w + 663552;          //      2,304 f
static const size_t o_den = o_S + 2304;            //     16,384 f

// short offsets inside o_w
static const size_t sw_w1h = 0;          // 524,288
static const size_t sw_w1l = 524288;
static const size_t sw_w2h = 1048576;    // 65,536
static const size_t sw_w2l = 1114112;
static const size_t sw_g1h = 1179648;    // 36,864 ([128][288])
static const size_t sw_g1l = 1216512;
static const size_t sw_g2h = 1253376;
static const size_t sw_g2l = 1290240;

typedef __attribute__((ext_vector_type(8))) __bf16 bf16x8;
typedef __attribute__((ext_vector_type(4))) float f32x4;

__device__ __forceinline__ float diag_w() {
    // identical fp32 ops to the generic path evaluated at xy == 1.0f
    float dd = logf(1.0f + sqrtf(1.0f*1.0f - 1.0f + 1e-7f));
    dd = fminf(fmaxf(dd, 1e-6f), 200.0f);
    float x2 = expf(-dd);
    return expf(x2) - 1.0f;
}

__device__ __forceinline__ unsigned short f2bf(float f) {
    unsigned int u = __float_as_uint(f);
    u += 0x7FFFu + ((u >> 16) & 1u);   // RNE
    return (unsigned short)(u >> 16);
}
__device__ __forceinline__ float bf2f(unsigned short h) {
    return __uint_as_float((unsigned int)h << 16);
}

// ---------------------------------------------------------------- utilities
__global__ void k_zero(float* __restrict__ p, size_t n) {
    size_t i = (size_t)blockIdx.x * 256 + threadIdx.x;
    size_t stride = (size_t)gridDim.x * 256;
    for (; i < n; i += stride) p[i] = 0.f;
}

// den init + S zero (merged)
__global__ void k_init(float* __restrict__ den, const int* __restrict__ seq,
                       float* __restrict__ S) {
    int r = blockIdx.x * 256 + threadIdx.x;   // 16384 total
    den[r] = (float)seq[r >> 11] + diag_w();
    if (r < BB * DHP) S[r] = 0.f;
}

// w1 + w2 fp32 -> (hi,lo) bf16 split in one launch
__global__ void k_split_w(const float* __restrict__ w1, const float* __restrict__ w2,
                          unsigned short* __restrict__ h1, unsigned short* __restrict__ l1,
                          unsigned short* __restrict__ h2, unsigned short* __restrict__ l2) {
    size_t i = ((size_t)blockIdx.x * 256 + threadIdx.x) * 4;
    const float* src; unsigned short *h, *l; size_t o;
    if (i < (size_t)D1_ * DV_) { src = w1; h = h1; l = l1; o = i; }
    else {
        o = i - (size_t)D1_ * DV_;
        if (o >= (size_t)D2_ * D1_) return;
        src = w2; h = h2; l = l2;
    }
    float4 v = *(const float4*)(src + o);
    ushort4 hv, lv;
    hv.x = f2bf(v.x); lv.x = f2bf(v.x - bf2f(hv.x));
    hv.y = f2bf(v.y); lv.y = f2bf(v.y - bf2f(hv.y));
    hv.z = f2bf(v.z); lv.z = f2bf(v.z - bf2f(hv.z));
    hv.w = f2bf(v.w); lv.w = f2bf(v.w - bf2f(hv.w));
    *(ushort4*)(h + o) = hv;
    *(ushort4*)(l + o) = lv;
}

// inputs[:, :, :1024] (row stride 1152) -> split [16384][1024]
__global__ void k_split_in(const float* __restrict__ inputs,
                           unsigned short* __restrict__ h,
                           unsigned short* __restrict__ l) {
    size_t i = ((size_t)blockIdx.x * 256 + threadIdx.x) * 4;
    if (i >= (size_t)MTOT * DV_) return;
    int r = (int)(i >> 10), c = (int)(i & 1023);
    float4 v = *(const float4*)(inputs + (size_t)r * 1152 + c);
    ushort4 hv, lv;
    hv.x = f2bf(v.x); lv.x = f2bf(v.x - bf2f(hv.x));
    hv.y = f2bf(v.y); lv.y = f2bf(v.y - bf2f(hv.y));
    hv.z = f2bf(v.z); lv.z = f2bf(v.z - bf2f(hv.z));
    hv.w = f2bf(v.w); lv.w = f2bf(v.w - bf2f(hv.w));
    *(ushort4*)(h + i) = hv;
    *(ushort4*)(l + i) = lv;
}

// gw1/gw2 [257][128] -> transposed, padded, split [128][288]; blockIdx.y picks
__global__ void k_padgw_t(const float* __restrict__ g1, const float* __restrict__ g2,
                          unsigned short* __restrict__ h1, unsigned short* __restrict__ l1,
                          unsigned short* __restrict__ h2, unsigned short* __restrict__ l2) {
    int i = blockIdx.x * 256 + threadIdx.x;   // DG*DHP = 36864
    if (i >= DG_ * DHP) return;
    const float* g = blockIdx.y ? g2 : g1;
    unsigned short* th = blockIdx.y ? h2 : h1;
    unsigned short* tl = blockIdx.y ? l2 : l1;
    int c = i / DHP, k = i - c * DHP;
    float v = (k < DH_) ? g[k * DG_ + c] : 0.f;
    unsigned short hh = f2bf(v);
    th[i] = hh;
    tl[i] = f2bf(v - bf2f(hh));
}

// ------------------------------------------------- split-bf16x3 MFMA core
// a*b ~ ah*bh + al*bh + ah*bl (error ~2^-17 rel ~ fp32).
#define LOADK(S, k0) \
    _Pragma("unroll") \
    for (int t = 0; t < 4; ++t) { \
        size_t ao = (size_t)(r0 + t*16 + m) * lda + (k0) + q*8; \
        size_t bo = (size_t)(c0 + t*16 + m) * ldb + (k0) + q*8; \
        ah##S[t] = *(const bf16x8*)(Ah + ao); \
        al##S[t] = *(const bf16x8*)(Al + ao); \
        bh##S[t] = *(const bf16x8*)(Bh + bo); \
        bl##S[t] = *(const bf16x8*)(Bl + bo); \
    }
#define MFMAK(S) \
    _Pragma("unroll") \
    for (int mi = 0; mi < 4; ++mi) \
        _Pragma("unroll") \
        for (int nj = 0; nj < 4; ++nj) { \
            acc[mi][nj] = __builtin_amdgcn_mfma_f32_16x16x32_bf16(ah##S[mi], bh##S[nj], acc[mi][nj], 0, 0, 0); \
            acc[mi][nj] = __builtin_amdgcn_mfma_f32_16x16x32_bf16(al##S[mi], bh##S[nj], acc[mi][nj], 0, 0, 0); \
            acc[mi][nj] = __builtin_amdgcn_mfma_f32_16x16x32_bf16(ah##S[mi], bl##S[nj], acc[mi][nj], 0, 0, 0); \
        }

// ------------------------------------------------- MLP1: pre-split A + XCD swizzle
// A pre-split by k_split_in (streaming; removes the in-register cvt that made
// r8 VALU-bound: 768 VALU cyc vs 384 MFMA cyc per chunk). XCD swizzle keeps
// one 128-row A-panel's 4 column-tiles on one XCD (r8: FETCH 234 -> 41 MB).
__global__ __launch_bounds__(256, 1) void gemm_mlp1(
    const unsigned short* __restrict__ Ah, const unsigned short* __restrict__ Al,
    const unsigned short* __restrict__ Bh, const unsigned short* __restrict__ Bl,
    const float* __restrict__ bias,
    unsigned short* __restrict__ Ch, unsigned short* __restrict__ Cl)
{
    const int ib = blockIdx.x;               // 512 blocks
    const int x = ib & 7, slot = ib >> 3;    // xcd lane, 64 slots
    const int cc = slot & 3, g = slot >> 2;  // col-tile, panel group
    const int row0 = (x + 8 * g) * 128, col0 = cc * 128;
    const int lda = DV_, ldb = DV_;
    const int wave = threadIdx.x >> 6, lane = threadIdx.x & 63;
    const int r0 = row0 + (wave >> 1) * 64, c0 = col0 + (wave & 1) * 64;
    const int q = lane >> 4, m = lane & 15;
    f32x4 acc[4][4];
#pragma unroll
    for (int a = 0; a < 4; ++a)
#pragma unroll
        for (int c = 0; c < 4; ++c) acc[a][c] = (f32x4){0.f, 0.f, 0.f, 0.f};
    bf16x8 ah0[4], al0[4], bh0[4], bl0[4];
    bf16x8 ah1[4], al1[4], bh1[4], bl1[4];
    LOADK(0, 0)
    for (int k0 = 0; k0 + 64 <= DV_; k0 += 64) {
        LOADK(1, k0 + 32)
        MFMAK(0)
        if (k0 + 64 < DV_) { LOADK(0, k0 + 64) }
        MFMAK(1)
    }
    float bj[4];
#pragma unroll
    for (int nj = 0; nj < 4; ++nj) bj[nj] = bias[c0 + nj*16 + m];
#pragma unroll
    for (int mi = 0; mi < 4; ++mi)
#pragma unroll
        for (int nj = 0; nj < 4; ++nj)
#pragma unroll
            for (int t = 0; t < 4; ++t) {
                int i = r0 + mi*16 + q*4 + t;
                int j = c0 + nj*16 + m;
                float v = acc[mi][nj][t] + bj[nj];
                v = (v >= 0.f) ? v : NEGS * v;
                size_t o = (size_t)i * D1_ + j;
                unsigned short hh = f2bf(v);
                Ch[o] = hh;
                Cl[o] = f2bf(v - bf2f(hh));
            }
}

// ------------------------------------------------- generic split GEMM (NT)
// C = leaky(A*B^T + bias). Register double-buffer prefetch. (256,1): VGPR
// budget 512 (gfx950 default clamps to 64 -> spill).
__global__ __launch_bounds__(256, 1) void gemm_mfma_nt(
    const unsigned short* __restrict__ Ah, const unsigned short* __restrict__ Al, int lda,
    const unsigned short* __restrict__ Bh, const unsigned short* __restrict__ Bl, int ldb,
    const float* __restrict__ bias,
    float* __restrict__ Cf, unsigned short* __restrict__ Ch, unsigned short* __restrict__ Cl,
    int N, int K)
{
    const int row0 = blockIdx.y * 128, col0 = blockIdx.x * 128;
    const int wave = threadIdx.x >> 6, lane = threadIdx.x & 63;
    const int r0 = row0 + (wave >> 1) * 64, c0 = col0 + (wave & 1) * 64;
    const int q = lane >> 4, m = lane & 15;
    f32x4 acc[4][4];
#pragma unroll
    for (int a = 0; a < 4; ++a)
#pragma unroll
        for (int c = 0; c < 4; ++c) acc[a][c] = (f32x4){0.f, 0.f, 0.f, 0.f};
    bf16x8 ah0[4], al0[4], bh0[4], bl0[4];
    bf16x8 ah1[4], al1[4], bh1[4], bl1[4];
    LOADK(0, 0)
    int k0 = 0;
    for (; k0 + 64 <= K; k0 += 64) {
        LOADK(1, k0 + 32)
        MFMAK(0)
        if (k0 + 64 < K) { LOADK(0, k0 + 64) }
        MFMAK(1)
    }
    if (k0 < K) { MFMAK(0) }   // odd tail chunk (K=288)
    float bj[4];
#pragma unroll
    for (int nj = 0; nj < 4; ++nj)
        bj[nj] = bias ? bias[c0 + nj*16 + m] : 0.f;
#pragma unroll
    for (int mi = 0; mi < 4; ++mi)
#pragma unroll
        for (int nj = 0; nj < 4; ++nj)
#pragma unroll
            for (int t = 0; t < 4; ++t) {
                int i = r0 + mi*16 + q*4 + t;
                int j = c0 + nj*16 + m;
                float v = acc[mi][nj][t] + bj[nj];
                v = (v >= 0.f) ? v : NEGS * v;
                size_t o = (size_t)i * N + j;
                if (Cf) Cf[o] = v;
                if (Ch) {
                    unsigned short hh = f2bf(v);
                    Ch[o] = hh;
                    Cl[o] = f2bf(v - bf2f(hh));
                }
            }
}

// ------------------------------------------------- xy via bf16 MFMA (upper tri)
// Only observable effect: which pairs pass x2>0.8. Off-diag xy ~1e13 vs band
// [1,1.026]; bf16 error ~1e11 -> classification identical to fp32/f64.
#define XLOAD(S, k0) \
    _Pragma("unroll") \
    for (int t = 0; t < 4; ++t) { \
        af##S[t] = *(const bf16x8*)(base + (size_t)(r0 + t*16 + m) * DHP + (k0) + q*8); \
        bf##S[t] = *(const bf16x8*)(base + (size_t)(c0 + t*16 + m) * DHP + (k0) + q*8); \
    }
#define XMFMA(S) \
    _Pragma("unroll") \
    for (int mi = 0; mi < 4; ++mi) \
        _Pragma("unroll") \
        for (int nj = 0; nj < 4; ++nj) \
            acc[mi][nj] = __builtin_amdgcn_mfma_f32_16x16x32_bf16(af##S[mi], bf##S[nj], acc[mi][nj], 0, 0, 0);

__global__ __launch_bounds__(256, 1) void k_xy_mfma(
    const unsigned short* __restrict__ pxb, const float* __restrict__ px,
    const int* __restrict__ seq, float* __restrict__ den, float* __restrict__ accb)
{
    const int b = blockIdx.z;
    const int bx = blockIdx.x, by = blockIdx.y;
    if (bx < by) return;
    const int nb = seq[b];
    const int row0 = by * 128, col0 = bx * 128;
    if (row0 >= nb || col0 >= nb) return;
    const int wave = threadIdx.x >> 6, lane = threadIdx.x & 63;
    const int r0 = row0 + (wave >> 1) * 64, c0 = col0 + (wave & 1) * 64;
    if (c0 + 63 < r0 || r0 >= nb || c0 >= nb) return;   // wave-uniform exits
    const unsigned short* base = pxb + (size_t)b * TT * DHP;
    const int q = lane >> 4, m = lane & 15;
    f32x4 acc[4][4];
#pragma unroll
    for (int a = 0; a < 4; ++a)
#pragma unroll
        for (int c = 0; c < 4; ++c) acc[a][c] = (f32x4){0.f, 0.f, 0.f, 0.f};
    bf16x8 af0[4], bf0[4], af1[4], bf1[4];
    XLOAD(0, 0)
    int k0 = 0;
    for (; k0 + 64 <= DHP; k0 += 64) {
        XLOAD(1, k0 + 32)
        XMFMA(0)
        if (k0 + 64 < DHP) { XLOAD(0, k0 + 64) }
        XMFMA(1)
    }
    if (k0 < DHP) { XMFMA(0) }
    const float* b32 = px + (size_t)b * TT * DHP;
    float cj[4], ci[4][4];
#pragma unroll
    for (int nj = 0; nj < 4; ++nj) cj[nj] = b32[(size_t)(c0 + nj*16 + m) * DHP];
#pragma unroll
    for (int mi = 0; mi < 4; ++mi)
#pragma unroll
        for (int t = 0; t < 4; ++t) ci[mi][t] = b32[(size_t)(r0 + mi*16 + q*4 + t) * DHP];
#pragma unroll
    for (int mi = 0; mi < 4; ++mi)
#pragma unroll
        for (int nj = 0; nj < 4; ++nj)
#pragma unroll
            for (int t = 0; t < 4; ++t) {
                int i = r0 + mi*16 + q*4 + t;
                int j = c0 + nj*16 + m;
                if (i < j && j < nb) {
                    float xyv = 2.f * ci[mi][t] * cj[nj] - acc[mi][nj][t];
                    float xym = fmaxf(xyv, 1.0f);
                    // xym >= 1.026 => x2 <= 0.798 < 0.8: no correction
                    if (xym < 1.026f) {
                        float dd = logf(xym + sqrtf(xym * xym - 1.0f + 1e-7f));
                        dd = fminf(fmaxf(dd, 1e-6f), 200.0f);
                        float x2v = expf(-dd);
                        if (x2v > 0.8f) {
                            float w = expf(x2v) - 1.0f;
                            atomicAdd(&den[b * TT + i], w);
                            atomicAdd(&den[b * TT + j], w);
                            const float* pi = b32 + (size_t)i * DHP;
                            const float* pj = b32 + (size_t)j * DHP;
                            float* ai = accb + ((size_t)(b * TT + i)) * DHP;
                            float* aj = accb + ((size_t)(b * TT + j)) * DHP;
                            for (int d = 0; d < DHP; ++d) {
                                atomicAdd(&ai[d], w * pj[d]);
                                atomicAdd(&aj[d], w * pi[d]);
                            }
                        }
                    }
                }
            }
}

// ------------------------------------------------- expmap0 (px fp32 + bf16)
__global__ __launch_bounds__(256) void k_proj(
    const float* __restrict__ C2, const float* __restrict__ inputs,
    float* __restrict__ px, unsigned short* __restrict__ pxb)
{
    const int r = blockIdx.x;
    const int tid = threadIdx.x;
    float v = (tid < 128) ? C2[(size_t)r * 128 + tid]
                          : inputs[(size_t)r * 1152 + 1024 + (tid - 128)];
    float sq = v * v;
#pragma unroll
    for (int o = 32; o > 0; o >>= 1) sq += __shfl_down(sq, o, 64);
    __shared__ float wred[4];
    __shared__ float cs[2];
    if ((tid & 63) == 0) wred[tid >> 6] = sq;
    __syncthreads();
    if (tid == 0) {
        float n2 = fmaxf(wred[0] + wred[1] + wred[2] + wred[3], 1e-12f);
        float n = sqrtf(n2);
        cs[0] = coshf(n);
        cs[1] = sinhf(n) / n;
    }
    __syncthreads();
    float sv = cs[1] * v;
    px[(size_t)r * DHP + 1 + tid] = sv;
    pxb[(size_t)r * DHP + 1 + tid] = f2bf(sv);
    if (tid == 0) {
        px[(size_t)r * DHP] = cs[0];
        pxb[(size_t)r * DHP] = f2bf(cs[0]);
    }
    if (tid < DHP - DH_) {   // 31 pad zeros
        px[(size_t)r * DHP + DH_ + tid] = 0.f;
        pxb[(size_t)r * DHP + DH_ + tid] = 0;
    }
}

// ------------------------------------------------- per-batch valid column sum
__global__ __launch_bounds__(256) void k_ssum(
    const float* __restrict__ px, const int* __restrict__ seq,
    float* __restrict__ S)
{
    const int b = blockIdx.x, chunk = blockIdx.y, tid = threadIdx.x;
    const int nb = seq[b];
    const int j0 = chunk * 32;
    const int j1 = (j0 + 32 < nb) ? j0 + 32 : nb;
    float a0 = 0.f, a1 = 0.f;
    const bool hasB = (tid < DHP - 256);
    for (int j = j0; j < j1; ++j) {
        const float* row = px + ((size_t)(b * TT + j)) * DHP;
        a0 += row[tid];
        if (hasB) a1 += row[256 + tid];
    }
    if (j1 > j0) {
        atomicAdd(&S[b * DHP + tid], a0);
        if (hasB) atomicAdd(&S[b * DHP + 256 + tid], a1);
    }
}

// ------------------------------------------------- Y1 = (S + corr + wd*px)/den
// emits split bf16 for the downstream MFMA graph-conv
__global__ void k_y1(const float* __restrict__ accb, const float* __restrict__ S,
                     const float* __restrict__ den, const int* __restrict__ seq,
                     const float* __restrict__ px,
                     unsigned short* __restrict__ yh, unsigned short* __restrict__ yl)
{
    size_t idx = (size_t)blockIdx.x * 256 + threadIdx.x;
    if (idx >= NPX) return;
    int r = (int)(idx / DHP);
    int b = r >> 11, i = r & (TT - 1);
    int d = (int)(idx - (size_t)r * DHP);
    float out = 0.f;
    if (i < seq[b])
        out = (S[b * DHP + d] + accb[idx] + diag_w() * px[idx]) / den[r];
    unsigned short hh = f2bf(out);
    yh[idx] = hh;
    yl[idx] = f2bf(out - bf2f(hh));
}

// ------------------------------------------------- disadj @ px via dual scan
// disadj[i,j] = r^|i-j|: full matvec = fwd + bwd first-order recursions with
// HALO=128 warmup (carry decay r^128 ~ 3.5e-21 — sub-fp32-eps at any px scale).
__global__ __launch_bounds__(256) void k_band(
    const float* __restrict__ px,
    unsigned short* __restrict__ yh, unsigned short* __restrict__ yl)
{
    __shared__ float Fs[CH][DHP];   // 73,728 B
    const int b = blockIdx.y;
    const int i0 = blockIdx.x * CH;
    const int tid = threadIdx.x;
    const bool hasB = (tid < DHP - 256);
    const float r = expf(-INV_E);
    const float* base = px + (size_t)b * TT * DHP;

    // forward scan with left halo
    {
        const int jlo = (i0 - HALO > 0) ? i0 - HALO : 0;
        float LA = 0.f, LB = 0.f;
        for (int j = jlo; j < i0 + CH; ++j) {
            const float* row = base + (size_t)j * DHP;
            LA = fmaf(r, LA, row[tid]);
            if (hasB) LB = fmaf(r, LB, row[256 + tid]);
            if (j >= i0) {
                Fs[j - i0][tid] = LA;
                if (hasB) Fs[j - i0][256 + tid] = LB;
            }
        }
    }
    __syncthreads();
    // backward scan with right halo; emit y = F + G - px
    {
        const int jhi = (i0 + CH - 1 + HALO < TT - 1) ? i0 + CH - 1 + HALO : TT - 1;
        float RA = 0.f, RB = 0.f;
        for (int j = jhi; j >= i0; --j) {
            const float* row = base + (size_t)j * DHP;
            float pa = row[tid];
            float pb = hasB ? row[256 + tid] : 0.f;
            RA = fmaf(r, RA, pa);
            if (hasB) RB = fmaf(r, RB, pb);
            if (j < i0 + CH) {
                size_t o = ((size_t)(b * TT + j)) * DHP + tid;
                float ya = Fs[j - i0][tid] + RA - pa;
                unsigned short hh = f2bf(ya);
                yh[o] = hh; yl[o] = f2bf(ya - bf2f(hh));
                if (hasB) {
                    float yb = Fs[j - i0][256 + tid] + RB - pb;
                    size_t ob = o + 256;
                    unsigned short h2 = f2bf(yb);
                    yh[ob] = h2; yl[ob] = f2bf(yb - bf2f(h2));
                }
            }
        }
    }
}

// ------------------------------------------------- frame_prob
__global__ __launch_bounds__(256) void k_frame(
    const float* __restrict__ x1, const float* __restrict__ x2f,
    const float* __restrict__ cls_w, const float* __restrict__ cls_b,
    float* __restrict__ dout)
{
    const int r = blockIdx.x * 4 + (threadIdx.x >> 6);
    const int lane = threadIdx.x & 63;
    float s = 0.f;
#pragma unroll
    for (int t = 0; t < 2; ++t) {
        int g = lane + t * 64;
        float cw1 = cls_w[g];
        if (g == 0) cw1 = -cw1;      // signs: only dim 0 negated
        s += x1[(size_t)r * DG_ + g] * cw1;
        s += x2f[(size_t)r * DG_ + g] * cls_w[DG_ + g];
    }
#pragma unroll
    for (int o = 32; o > 0; o >>= 1) s += __shfl_down(s, o, 64);
    if (lane == 0) dout[8 + r] = 2.0f + 2.0f * s + cls_b[0];
}

// ------------------------------------------------- top-k MIL (bitonic sort)
__global__ __launch_bounds__(1024) void k_clas(
    const int* __restrict__ seq, float* __restrict__ dout)
{
    __shared__ float s[TT];
    const int b = blockIdx.x, tid = threadIdx.x;
    const int nb = seq[b];
    for (int t = tid; t < TT; t += 1024)
        s[t] = (t < nb) ? dout[8 + b * TT + t] : -1e30f;
    __syncthreads();
    for (int k = 2; k <= TT; k <<= 1)
        for (int j = k >> 1; j > 0; j >>= 1) {
            for (int i = tid; i < TT; i += 1024) {
                int ixj = i ^ j;
                if (ixj > i) {
                    float a = s[i], c = s[ixj];
                    bool descBlk = ((i & k) == 0);
                    if (descBlk ? (a < c) : (a > c)) { s[i] = c; s[ixj] = a; }
                }
            }
            __syncthreads();
        }
    const int kk = nb / 16 + 1;
    float part = 0.f;
    for (int t = tid; t < kk; t += 1024) part += s[t];
#pragma unroll
    for (int o = 32; o > 0; o >>= 1) part += __shfl_down(part, o, 64);
    __shared__ float wred[16];
    if ((tid & 63) == 0) wred[tid >> 6] = part;
    __syncthreads();
    if (tid == 0) {
        float mil = 0.f;
#pragma unroll
        for (int t = 0; t < 16; ++t) mil += wred[t];
        mil /= (float)kk;
        dout[b] = 1.f / (1.f + expf(-mil));
    }
}

// ---------------------------------------------------------------- launch
extern "C" void kernel_launch(void* const* d_in, const int* in_sizes, int n_in,
                              void* d_out, int out_size, void* d_ws, size_t ws_size,
                              hipStream_t stream) {
    (void)in_sizes; (void)n_in; (void)out_size; (void)ws_size;
    const float* inputs = (const float*)d_in[0];
    const int*   seq    = (const int*)d_in[1];
    const float* w1     = (const float*)d_in[2];
    const float* b1     = (const float*)d_in[3];
    const float* w2     = (const float*)d_in[4];
    const float* b2     = (const float*)d_in[5];
    const float* gw1    = (const float*)d_in[6];
    const float* gw2    = (const float*)d_in[7];
    const float* cls_w  = (const float*)d_in[8];
    const float* cls_b  = (const float*)d_in[9];
    float* dout = (float*)d_out;
    float* ws = (float*)d_ws;

    // o_big region: Ah/Al (MLP1 input split) -> px + pxb + y2 + y1
    unsigned short* Ah = (unsigned short*)(ws + o_big);
    unsigned short* Al = Ah + (size_t)MTOT * DV_;
    float* px  = ws + o_big;
    unsigned short* pxb = (unsigned short*)(ws + o_big + 4718592);
    unsigned short* y2h = (unsigned short*)(ws + o_big + 7077888);
    unsigned short* y2l = y2h + NPX;
    unsigned short* y1h = (unsigned short*)(ws + o_big + 11796480);
    unsigned short* y1l = y1h + NPX;
    // o_c1 region: C1h/C1l -> accb + x1
    unsigned short* C1h = (unsigned short*)(ws + o_c1);
    unsigned short* C1l = C1h + (size_t)MTOT * D1_;
    float* accb = ws + o_c1;
    float* x1   = ws + o_c1 + 4718592;
    // o_c2 region: C2 -> x2f
    float* C2  = ws + o_c2;
    float* x2f = ws + o_c2;
    // weights
    unsigned short* wsS = (unsigned short*)(ws + o_w);
    unsigned short *W1h = wsS + sw_w1h, *W1l = wsS + sw_w1l;
    unsigned short *W2h = wsS + sw_w2h, *W2l = wsS + sw_w2l;
    unsigned short *g1h = wsS + sw_g1h, *g1l = wsS + sw_g1l;
    unsigned short *g2h = wsS + sw_g2h, *g2l = wsS + sw_g2l;
    float* S   = ws + o_S;
    float* den = ws + o_den;

    // init + splits
    k_init<<<MTOT / 256, 256, 0, stream>>>(den, seq, S);
    k_split_in<<<16384, 256, 0, stream>>>(inputs, Ah, Al);
    k_split_w<<<576, 256, 0, stream>>>(w1, w2, W1h, W1l, W2h, W2l);
    k_padgw_t<<<dim3(144, 2), 256, 0, stream>>>(gw1, gw2, g1h, g1l, g2h, g2l);

    // MLP1: pre-split MFMA GEMM, XCD-swizzled
    gemm_mlp1<<<512, 256, 0, stream>>>(Ah, Al, W1h, W1l, b1, C1h, C1l);
    // MLP2
    gemm_mfma_nt<<<dim3(1, MTOT / 128), 256, 0, stream>>>(
        C1h, C1l, D1_, W2h, W2l, D1_, b2, C2, nullptr, nullptr, D2_, D1_);

    // expmap0 (px/pxb overwrite Ah region — Ah dead after MLP1)
    k_proj<<<MTOT, 256, 0, stream>>>(C2, inputs, px, pxb);

    // zero correction accumulator (overwrites C1 — dead after MLP2)
    k_zero<<<4096, 256, 0, stream>>>(accb, NPX);

    // valid column sums
    k_ssum<<<dim3(BB, TT / 32), 256, 0, stream>>>(px, seq, S);

    // Lorentz similarity via bf16 MFMA, upper triangle
    k_xy_mfma<<<dim3(TT / 128, TT / 128, BB), 256, 0, stream>>>(pxb, px, seq, den, accb);

    // Y1 = (S + corr + diag)/den -> split bf16
    k_y1<<<(int)(NPX / 256), 256, 0, stream>>>(accb, S, den, seq, px, y1h, y1l);

    // disadj @ px via dual scan -> split bf16
    k_band<<<dim3(TT / CH, BB), 256, 0, stream>>>(px, y2h, y2l);

    // graph-conv projections via MFMA
    gemm_mfma_nt<<<dim3(1, MTOT / 128), 256, 0, stream>>>(
        y1h, y1l, DHP, g1h, g1l, DHP, nullptr, x1, nullptr, nullptr, DG_, DHP);
    gemm_mfma_nt<<<dim3(1, MTOT / 128), 256, 0, stream>>>(
        y2h, y2l, DHP, g2h, g2l, DHP, nullptr, x2f, nullptr, nullptr, DG_, DHP);

    // frame_prob + MIL
    k_frame<<<MTOT / 4, 256, 0, stream>>>(x1, x2f, cls_w, cls_b, dout);
    k_clas<<<BB, 1024, 0, stream>>>(seq, dout);
}

// Round 10
// 500.879 us; speedup vs baseline: 1.1883x; 1.1883x over previous
//
#include <hip/hip_runtime.h>
#include <math.h>

// ---------------------------------------------------------------- constants
#define BB 8
#define TT 2048
#define DV_ 1024
#define DA_ 128
#define D1_ 512
#define D2_ 128
#define DH_ 257
#define DHP 288            // padded (zeros): divisible by 32 for MFMA K-chunks
#define DG_ 128
#define MTOT (BB*TT)       // 16384 rows
#define NPX ((size_t)MTOT*DHP)

#define NEGS 0.01f
#define INV_E 0.36787944117144233f
#define CH 64              // scan chunk rows
#define HALO 128           // r^128 ~ 3.5e-21: carry beyond halo is sub-eps

#define RS 40              // MLP1 LDS row stride (hw): 80 B -> 20-bank step/row,
                           // worst aliasing 2-way (free, m136); 32 hw would be 8-way
#define BKC 32             // MLP1 K-chunk (halfwords)

// ---------------------------------------------------------------- workspace
static const size_t o_big = 0;                     // 16,777,216 f
static const size_t o_c1  = 16777216;              //  8,388,608 f
static const size_t o_c2  = o_c1 + 8388608;        //  2,097,152 f
static const size_t o_w   = o_c2 + 2097152;        //    663,552 f (split weights)
static const size_t o_S   = o_w + 663552;          //      2,304 f
static const size_t o_den = o_S + 2304;            //     16,384 f

// short offsets inside o_w
static const size_t sw_w1h = 0;          // 524,288
static const size_t sw_w1l = 524288;
static const size_t sw_w2h = 1048576;    // 65,536
static const size_t sw_w2l = 1114112;
static const size_t sw_g1h = 1179648;    // 36,864 ([128][288])
static const size_t sw_g1l = 1216512;
static const size_t sw_g2h = 1253376;
static const size_t sw_g2l = 1290240;

typedef __attribute__((ext_vector_type(8))) __bf16 bf16x8;
typedef __attribute__((ext_vector_type(8))) unsigned short us8;
typedef __attribute__((ext_vector_type(4))) float f32x4;

__device__ __forceinline__ float diag_w() {
    // identical fp32 ops to the generic path evaluated at xy == 1.0f
    float dd = logf(1.0f + sqrtf(1.0f*1.0f - 1.0f + 1e-7f));
    dd = fminf(fmaxf(dd, 1e-6f), 200.0f);
    float x2 = expf(-dd);
    return expf(x2) - 1.0f;
}

__device__ __forceinline__ unsigned short f2bf(float f) {
    unsigned int u = __float_as_uint(f);
    u += 0x7FFFu + ((u >> 16) & 1u);   // RNE
    return (unsigned short)(u >> 16);
}
__device__ __forceinline__ float bf2f(unsigned short h) {
    return __uint_as_float((unsigned int)h << 16);
}

// ---------------------------------------------------------------- utilities
__global__ void k_zero(float* __restrict__ p, size_t n) {
    size_t i = (size_t)blockIdx.x * 256 + threadIdx.x;
    size_t stride = (size_t)gridDim.x * 256;
    for (; i < n; i += stride) p[i] = 0.f;
}

// den init + S zero (merged)
__global__ void k_init(float* __restrict__ den, const int* __restrict__ seq,
                       float* __restrict__ S) {
    int r = blockIdx.x * 256 + threadIdx.x;   // 16384 total
    den[r] = (float)seq[r >> 11] + diag_w();
    if (r < BB * DHP) S[r] = 0.f;
}

// w1 + w2 fp32 -> (hi,lo) bf16 split in one launch
__global__ void k_split_w(const float* __restrict__ w1, const float* __restrict__ w2,
                          unsigned short* __restrict__ h1, unsigned short* __restrict__ l1,
                          unsigned short* __restrict__ h2, unsigned short* __restrict__ l2) {
    size_t i = ((size_t)blockIdx.x * 256 + threadIdx.x) * 4;
    const float* src; unsigned short *h, *l; size_t o;
    if (i < (size_t)D1_ * DV_) { src = w1; h = h1; l = l1; o = i; }
    else {
        o = i - (size_t)D1_ * DV_;
        if (o >= (size_t)D2_ * D1_) return;
        src = w2; h = h2; l = l2;
    }
    float4 v = *(const float4*)(src + o);
    ushort4 hv, lv;
    hv.x = f2bf(v.x); lv.x = f2bf(v.x - bf2f(hv.x));
    hv.y = f2bf(v.y); lv.y = f2bf(v.y - bf2f(hv.y));
    hv.z = f2bf(v.z); lv.z = f2bf(v.z - bf2f(hv.z));
    hv.w = f2bf(v.w); lv.w = f2bf(v.w - bf2f(hv.w));
    *(ushort4*)(h + o) = hv;
    *(ushort4*)(l + o) = lv;
}

// inputs[:, :, :1024] (row stride 1152) -> split [16384][1024]
__global__ void k_split_in(const float* __restrict__ inputs,
                           unsigned short* __restrict__ h,
                           unsigned short* __restrict__ l) {
    size_t i = ((size_t)blockIdx.x * 256 + threadIdx.x) * 4;
    if (i >= (size_t)MTOT * DV_) return;
    int r = (int)(i >> 10), c = (int)(i & 1023);
    float4 v = *(const float4*)(inputs + (size_t)r * 1152 + c);
    ushort4 hv, lv;
    hv.x = f2bf(v.x); lv.x = f2bf(v.x - bf2f(hv.x));
    hv.y = f2bf(v.y); lv.y = f2bf(v.y - bf2f(hv.y));
    hv.z = f2bf(v.z); lv.z = f2bf(v.z - bf2f(hv.z));
    hv.w = f2bf(v.w); lv.w = f2bf(v.w - bf2f(hv.w));
    *(ushort4*)(h + i) = hv;
    *(ushort4*)(l + i) = lv;
}

// gw1/gw2 [257][128] -> transposed, padded, split [128][288]; blockIdx.y picks
__global__ void k_padgw_t(const float* __restrict__ g1, const float* __restrict__ g2,
                          unsigned short* __restrict__ h1, unsigned short* __restrict__ l1,
                          unsigned short* __restrict__ h2, unsigned short* __restrict__ l2) {
    int i = blockIdx.x * 256 + threadIdx.x;   // DG*DHP = 36864
    if (i >= DG_ * DHP) return;
    const float* g = blockIdx.y ? g2 : g1;
    unsigned short* th = blockIdx.y ? h2 : h1;
    unsigned short* tl = blockIdx.y ? l2 : l1;
    int c = i / DHP, k = i - c * DHP;
    float v = (k < DH_) ? g[k * DG_ + c] : 0.f;
    unsigned short hh = f2bf(v);
    th[i] = hh;
    tl[i] = f2bf(v - bf2f(hh));
}

// ------------------------------------------------- MLP1: LDS-staged split GEMM
// r6-r9: direct-global K-loop plateaued at ~132us (MfmaUtil 15%, ~9k stall
// cyc/iter at 2 waves/SIMD). LDS double-buffer (m93 pattern): coalesced 16B
// global loads -> ds_write_b128 -> ds_read_b128 frags; 1 barrier/chunk.
// 80 KB LDS -> 2 blocks/CU. XCD swizzle kept (r8: FETCH 234 -> 41 MB).
__global__ __launch_bounds__(256, 1) void gemm_mlp1(
    const unsigned short* __restrict__ Ah, const unsigned short* __restrict__ Al,
    const unsigned short* __restrict__ Bh, const unsigned short* __restrict__ Bl,
    const float* __restrict__ bias,
    unsigned short* __restrict__ Ch, unsigned short* __restrict__ Cl)
{
    __shared__ unsigned short sm[2][4][128 * RS];   // [buf][Ah,Al,Bh,Bl] = 80 KB
    const int ib = blockIdx.x;               // 512 blocks
    const int x = ib & 7, slot = ib >> 3;    // xcd lane, 64 slots
    const int cc = slot & 3, g = slot >> 2;  // col-tile, panel group
    const int row0 = (x + 8 * g) * 128, col0 = cc * 128;
    const int tid = threadIdx.x;
    const int wave = tid >> 6, lane = tid & 63;
    const int r0w = (wave >> 1) * 64, c0w = (wave & 1) * 64;   // block-local
    const int q = lane >> 4, m = lane & 15;
    // staging: thread covers rows srow and srow+64, 8-hw col slice
    const int srow = tid >> 2, scol = (tid & 3) << 3;
    const size_t gA0 = (size_t)(row0 + srow) * DV_ + scol;
    const size_t gA1 = (size_t)(row0 + srow + 64) * DV_ + scol;
    const size_t gB0 = (size_t)(col0 + srow) * DV_ + scol;
    const size_t gB1 = (size_t)(col0 + srow + 64) * DV_ + scol;
    const int s0 = srow * RS + scol, s1 = (srow + 64) * RS + scol;

    us8 rA0h, rA1h, rA0l, rA1l, rB0h, rB1h, rB0l, rB1l;
    rA0h = *(const us8*)(Ah + gA0); rA1h = *(const us8*)(Ah + gA1);
    rA0l = *(const us8*)(Al + gA0); rA1l = *(const us8*)(Al + gA1);
    rB0h = *(const us8*)(Bh + gB0); rB1h = *(const us8*)(Bh + gB1);
    rB0l = *(const us8*)(Bl + gB0); rB1l = *(const us8*)(Bl + gB1);
    *(us8*)&sm[0][0][s0] = rA0h; *(us8*)&sm[0][0][s1] = rA1h;
    *(us8*)&sm[0][1][s0] = rA0l; *(us8*)&sm[0][1][s1] = rA1l;
    *(us8*)&sm[0][2][s0] = rB0h; *(us8*)&sm[0][2][s1] = rB1h;
    *(us8*)&sm[0][3][s0] = rB0l; *(us8*)&sm[0][3][s1] = rB1l;
    __syncthreads();

    f32x4 acc[4][4];
#pragma unroll
    for (int a = 0; a < 4; ++a)
#pragma unroll
        for (int c = 0; c < 4; ++c) acc[a][c] = (f32x4){0.f, 0.f, 0.f, 0.f};

    const int NC = DV_ / BKC;   // 32 chunks
    for (int kc = 0; kc < NC; ++kc) {
        const int buf = kc & 1;
        const bool more = (kc + 1 < NC);
        if (more) {   // issue next chunk's global loads (latency hidden by MFMA)
            const size_t o = (size_t)(kc + 1) * BKC;
            rA0h = *(const us8*)(Ah + gA0 + o); rA1h = *(const us8*)(Ah + gA1 + o);
            rA0l = *(const us8*)(Al + gA0 + o); rA1l = *(const us8*)(Al + gA1 + o);
            rB0h = *(const us8*)(Bh + gB0 + o); rB1h = *(const us8*)(Bh + gB1 + o);
            rB0l = *(const us8*)(Bl + gB0 + o); rB1l = *(const us8*)(Bl + gB1 + o);
        }
        bf16x8 fah[4], fal[4], fbh[4], fbl[4];
#pragma unroll
        for (int t = 0; t < 4; ++t) {
            const int ra = (r0w + t*16 + m) * RS + q*8;
            const int rb = (c0w + t*16 + m) * RS + q*8;
            fah[t] = *(const bf16x8*)&sm[buf][0][ra];
            fal[t] = *(const bf16x8*)&sm[buf][1][ra];
            fbh[t] = *(const bf16x8*)&sm[buf][2][rb];
            fbl[t] = *(const bf16x8*)&sm[buf][3][rb];
        }
#pragma unroll
        for (int mi = 0; mi < 4; ++mi)
#pragma unroll
            for (int nj = 0; nj < 4; ++nj) {
                acc[mi][nj] = __builtin_amdgcn_mfma_f32_16x16x32_bf16(fah[mi], fbh[nj], acc[mi][nj], 0, 0, 0);
                acc[mi][nj] = __builtin_amdgcn_mfma_f32_16x16x32_bf16(fal[mi], fbh[nj], acc[mi][nj], 0, 0, 0);
                acc[mi][nj] = __builtin_amdgcn_mfma_f32_16x16x32_bf16(fah[mi], fbl[nj], acc[mi][nj], 0, 0, 0);
            }
        if (more) {
            const int nb = buf ^ 1;
            *(us8*)&sm[nb][0][s0] = rA0h; *(us8*)&sm[nb][0][s1] = rA1h;
            *(us8*)&sm[nb][1][s0] = rA0l; *(us8*)&sm[nb][1][s1] = rA1l;
            *(us8*)&sm[nb][2][s0] = rB0h; *(us8*)&sm[nb][2][s1] = rB1h;
            *(us8*)&sm[nb][3][s0] = rB0l; *(us8*)&sm[nb][3][s1] = rB1l;
        }
        __syncthreads();
    }
    float bj[4];
#pragma unroll
    for (int nj = 0; nj < 4; ++nj) bj[nj] = bias[col0 + c0w + nj*16 + m];
#pragma unroll
    for (int mi = 0; mi < 4; ++mi)
#pragma unroll
        for (int nj = 0; nj < 4; ++nj)
#pragma unroll
            for (int t = 0; t < 4; ++t) {
                int i = row0 + r0w + mi*16 + q*4 + t;
                int j = col0 + c0w + nj*16 + m;
                float v = acc[mi][nj][t] + bj[nj];
                v = (v >= 0.f) ? v : NEGS * v;
                size_t o = (size_t)i * D1_ + j;
                unsigned short hh = f2bf(v);
                Ch[o] = hh;
                Cl[o] = f2bf(v - bf2f(hh));
            }
}

// ------------------------------------------------- split-bf16x3 MFMA core
#define LOADK(S, k0) \
    _Pragma("unroll") \
    for (int t = 0; t < 4; ++t) { \
        size_t ao = (size_t)(r0 + t*16 + m) * lda + (k0) + q*8; \
        size_t bo = (size_t)(c0 + t*16 + m) * ldb + (k0) + q*8; \
        ah##S[t] = *(const bf16x8*)(Ah + ao); \
        al##S[t] = *(const bf16x8*)(Al + ao); \
        bh##S[t] = *(const bf16x8*)(Bh + bo); \
        bl##S[t] = *(const bf16x8*)(Bl + bo); \
    }
#define MFMAK(S) \
    _Pragma("unroll") \
    for (int mi = 0; mi < 4; ++mi) \
        _Pragma("unroll") \
        for (int nj = 0; nj < 4; ++nj) { \
            acc[mi][nj] = __builtin_amdgcn_mfma_f32_16x16x32_bf16(ah##S[mi], bh##S[nj], acc[mi][nj], 0, 0, 0); \
            acc[mi][nj] = __builtin_amdgcn_mfma_f32_16x16x32_bf16(al##S[mi], bh##S[nj], acc[mi][nj], 0, 0, 0); \
            acc[mi][nj] = __builtin_amdgcn_mfma_f32_16x16x32_bf16(ah##S[mi], bl##S[nj], acc[mi][nj], 0, 0, 0); \
        }

// ------------------------------------------------- generic split GEMM (NT)
// C = leaky(A*B^T + bias). Register double-buffer prefetch. (256,1): VGPR
// budget 512 (gfx950 default clamps to 64 -> spill).
__global__ __launch_bounds__(256, 1) void gemm_mfma_nt(
    const unsigned short* __restrict__ Ah, const unsigned short* __restrict__ Al, int lda,
    const unsigned short* __restrict__ Bh, const unsigned short* __restrict__ Bl, int ldb,
    const float* __restrict__ bias,
    float* __restrict__ Cf, unsigned short* __restrict__ Ch, unsigned short* __restrict__ Cl,
    int N, int K)
{
    const int row0 = blockIdx.y * 128, col0 = blockIdx.x * 128;
    const int wave = threadIdx.x >> 6, lane = threadIdx.x & 63;
    const int r0 = row0 + (wave >> 1) * 64, c0 = col0 + (wave & 1) * 64;
    const int q = lane >> 4, m = lane & 15;
    f32x4 acc[4][4];
#pragma unroll
    for (int a = 0; a < 4; ++a)
#pragma unroll
        for (int c = 0; c < 4; ++c) acc[a][c] = (f32x4){0.f, 0.f, 0.f, 0.f};
    bf16x8 ah0[4], al0[4], bh0[4], bl0[4];
    bf16x8 ah1[4], al1[4], bh1[4], bl1[4];
    LOADK(0, 0)
    int k0 = 0;
    for (; k0 + 64 <= K; k0 += 64) {
        LOADK(1, k0 + 32)
        MFMAK(0)
        if (k0 + 64 < K) { LOADK(0, k0 + 64) }
        MFMAK(1)
    }
    if (k0 < K) { MFMAK(0) }   // odd tail chunk (K=288)
    float bj[4];
#pragma unroll
    for (int nj = 0; nj < 4; ++nj)
        bj[nj] = bias ? bias[c0 + nj*16 + m] : 0.f;
#pragma unroll
    for (int mi = 0; mi < 4; ++mi)
#pragma unroll
        for (int nj = 0; nj < 4; ++nj)
#pragma unroll
            for (int t = 0; t < 4; ++t) {
                int i = r0 + mi*16 + q*4 + t;
                int j = c0 + nj*16 + m;
                float v = acc[mi][nj][t] + bj[nj];
                v = (v >= 0.f) ? v : NEGS * v;
                size_t o = (size_t)i * N + j;
                if (Cf) Cf[o] = v;
                if (Ch) {
                    unsigned short hh = f2bf(v);
                    Ch[o] = hh;
                    Cl[o] = f2bf(v - bf2f(hh));
                }
            }
}

// ------------------------------------------------- merged graph-conv GEMMs
// x1 = leaky(y1 @ g1), x2 = leaky(y2 @ g2) in one launch (blockIdx.z picks);
// separate launches were 128 blocks = 0.5 blocks/CU each.
__global__ __launch_bounds__(256, 1) void gemm_gc(
    const unsigned short* __restrict__ A1h, const unsigned short* __restrict__ A1l,
    const unsigned short* __restrict__ A2h, const unsigned short* __restrict__ A2l,
    const unsigned short* __restrict__ G1h, const unsigned short* __restrict__ G1l,
    const unsigned short* __restrict__ G2h, const unsigned short* __restrict__ G2l,
    float* __restrict__ X1, float* __restrict__ X2)
{
    const int z = blockIdx.z;
    const unsigned short* Ah = z ? A2h : A1h;
    const unsigned short* Al = z ? A2l : A1l;
    const unsigned short* Bh = z ? G2h : G1h;
    const unsigned short* Bl = z ? G2l : G1l;
    float* Cf = z ? X2 : X1;
    const int lda = DHP, ldb = DHP;
    const int row0 = blockIdx.y * 128, col0 = 0;
    const int wave = threadIdx.x >> 6, lane = threadIdx.x & 63;
    const int r0 = row0 + (wave >> 1) * 64, c0 = col0 + (wave & 1) * 64;
    const int q = lane >> 4, m = lane & 15;
    f32x4 acc[4][4];
#pragma unroll
    for (int a = 0; a < 4; ++a)
#pragma unroll
        for (int c = 0; c < 4; ++c) acc[a][c] = (f32x4){0.f, 0.f, 0.f, 0.f};
    bf16x8 ah0[4], al0[4], bh0[4], bl0[4];
    bf16x8 ah1[4], al1[4], bh1[4], bl1[4];
    LOADK(0, 0)
    int k0 = 0;
    for (; k0 + 64 <= DHP; k0 += 64) {
        LOADK(1, k0 + 32)
        MFMAK(0)
        if (k0 + 64 < DHP) { LOADK(0, k0 + 64) }
        MFMAK(1)
    }
    if (k0 < DHP) { MFMAK(0) }   // K=288 tail
#pragma unroll
    for (int mi = 0; mi < 4; ++mi)
#pragma unroll
        for (int nj = 0; nj < 4; ++nj)
#pragma unroll
            for (int t = 0; t < 4; ++t) {
                int i = r0 + mi*16 + q*4 + t;
                int j = c0 + nj*16 + m;
                float v = acc[mi][nj][t];
                v = (v >= 0.f) ? v : NEGS * v;
                Cf[(size_t)i * DG_ + j] = v;
            }
}

// ------------------------------------------------- xy via bf16 MFMA (upper tri)
// Only observable effect: which pairs pass x2>0.8. Off-diag xy ~1e13 vs band
// [1,1.026]; bf16 error ~1e11 -> classification identical to fp32/f64.
#define XLOAD(S, k0) \
    _Pragma("unroll") \
    for (int t = 0; t < 4; ++t) { \
        af##S[t] = *(const bf16x8*)(base + (size_t)(r0 + t*16 + m) * DHP + (k0) + q*8); \
        bf##S[t] = *(const bf16x8*)(base + (size_t)(c0 + t*16 + m) * DHP + (k0) + q*8); \
    }
#define XMFMA(S) \
    _Pragma("unroll") \
    for (int mi = 0; mi < 4; ++mi) \
        _Pragma("unroll") \
        for (int nj = 0; nj < 4; ++nj) \
            acc[mi][nj] = __builtin_amdgcn_mfma_f32_16x16x32_bf16(af##S[mi], bf##S[nj], acc[mi][nj], 0, 0, 0);

__global__ __launch_bounds__(256, 1) void k_xy_mfma(
    const unsigned short* __restrict__ pxb, const float* __restrict__ px,
    const int* __restrict__ seq, float* __restrict__ den, float* __restrict__ accb)
{
    const int b = blockIdx.z;
    const int bx = blockIdx.x, by = blockIdx.y;
    if (bx < by) return;
    const int nb = seq[b];
    const int row0 = by * 128, col0 = bx * 128;
    if (row0 >= nb || col0 >= nb) return;
    const int wave = threadIdx.x >> 6, lane = threadIdx.x & 63;
    const int r0 = row0 + (wave >> 1) * 64, c0 = col0 + (wave & 1) * 64;
    if (c0 + 63 < r0 || r0 >= nb || c0 >= nb) return;   // wave-uniform exits
    const unsigned short* base = pxb + (size_t)b * TT * DHP;
    const int q = lane >> 4, m = lane & 15;
    f32x4 acc[4][4];
#pragma unroll
    for (int a = 0; a < 4; ++a)
#pragma unroll
        for (int c = 0; c < 4; ++c) acc[a][c] = (f32x4){0.f, 0.f, 0.f, 0.f};
    bf16x8 af0[4], bf0[4], af1[4], bf1[4];
    XLOAD(0, 0)
    int k0 = 0;
    for (; k0 + 64 <= DHP; k0 += 64) {
        XLOAD(1, k0 + 32)
        XMFMA(0)
        if (k0 + 64 < DHP) { XLOAD(0, k0 + 64) }
        XMFMA(1)
    }
    if (k0 < DHP) { XMFMA(0) }
    const float* b32 = px + (size_t)b * TT * DHP;
    float cj[4], ci[4][4];
#pragma unroll
    for (int nj = 0; nj < 4; ++nj) cj[nj] = b32[(size_t)(c0 + nj*16 + m) * DHP];
#pragma unroll
    for (int mi = 0; mi < 4; ++mi)
#pragma unroll
        for (int t = 0; t < 4; ++t) ci[mi][t] = b32[(size_t)(r0 + mi*16 + q*4 + t) * DHP];
#pragma unroll
    for (int mi = 0; mi < 4; ++mi)
#pragma unroll
        for (int nj = 0; nj < 4; ++nj)
#pragma unroll
            for (int t = 0; t < 4; ++t) {
                int i = r0 + mi*16 + q*4 + t;
                int j = c0 + nj*16 + m;
                if (i < j && j < nb) {
                    float xyv = 2.f * ci[mi][t] * cj[nj] - acc[mi][nj][t];
                    float xym = fmaxf(xyv, 1.0f);
                    // xym >= 1.026 => x2 <= 0.798 < 0.8: no correction
                    if (xym < 1.026f) {
                        float dd = logf(xym + sqrtf(xym * xym - 1.0f + 1e-7f));
                        dd = fminf(fmaxf(dd, 1e-6f), 200.0f);
                        float x2v = expf(-dd);
                        if (x2v > 0.8f) {
                            float w = expf(x2v) - 1.0f;
                            atomicAdd(&den[b * TT + i], w);
                            atomicAdd(&den[b * TT + j], w);
                            const float* pi = b32 + (size_t)i * DHP;
                            const float* pj = b32 + (size_t)j * DHP;
                            float* ai = accb + ((size_t)(b * TT + i)) * DHP;
                            float* aj = accb + ((size_t)(b * TT + j)) * DHP;
                            for (int d = 0; d < DHP; ++d) {
                                atomicAdd(&ai[d], w * pj[d]);
                                atomicAdd(&aj[d], w * pi[d]);
                            }
                        }
                    }
                }
            }
}

// ------------------------------------------------- expmap0 (px fp32 + bf16)
__global__ __launch_bounds__(256) void k_proj(
    const float* __restrict__ C2, const float* __restrict__ inputs,
    float* __restrict__ px, unsigned short* __restrict__ pxb)
{
    const int r = blockIdx.x;
    const int tid = threadIdx.x;
    float v = (tid < 128) ? C2[(size_t)r * 128 + tid]
                          : inputs[(size_t)r * 1152 + 1024 + (tid - 128)];
    float sq = v * v;
#pragma unroll
    for (int o = 32; o > 0; o >>= 1) sq += __shfl_down(sq, o, 64);
    __shared__ float wred[4];
    __shared__ float cs[2];
    if ((tid & 63) == 0) wred[tid >> 6] = sq;
    __syncthreads();
    if (tid == 0) {
        float n2 = fmaxf(wred[0] + wred[1] + wred[2] + wred[3], 1e-12f);
        float n = sqrtf(n2);
        cs[0] = coshf(n);
        cs[1] = sinhf(n) / n;
    }
    __syncthreads();
    float sv = cs[1] * v;
    px[(size_t)r * DHP + 1 + tid] = sv;
    pxb[(size_t)r * DHP + 1 + tid] = f2bf(sv);
    if (tid == 0) {
        px[(size_t)r * DHP] = cs[0];
        pxb[(size_t)r * DHP] = f2bf(cs[0]);
    }
    if (tid < DHP - DH_) {   // 31 pad zeros
        px[(size_t)r * DHP + DH_ + tid] = 0.f;
        pxb[(size_t)r * DHP + DH_ + tid] = 0;
    }
}

// ------------------------------------------------- per-batch valid column sum
__global__ __launch_bounds__(256) void k_ssum(
    const float* __restrict__ px, const int* __restrict__ seq,
    float* __restrict__ S)
{
    const int b = blockIdx.x, chunk = blockIdx.y, tid = threadIdx.x;
    const int nb = seq[b];
    const int j0 = chunk * 32;
    const int j1 = (j0 + 32 < nb) ? j0 + 32 : nb;
    float a0 = 0.f, a1 = 0.f;
    const bool hasB = (tid < DHP - 256);
    for (int j = j0; j < j1; ++j) {
        const float* row = px + ((size_t)(b * TT + j)) * DHP;
        a0 += row[tid];
        if (hasB) a1 += row[256 + tid];
    }
    if (j1 > j0) {
        atomicAdd(&S[b * DHP + tid], a0);
        if (hasB) atomicAdd(&S[b * DHP + 256 + tid], a1);
    }
}

// ------------------------------------------------- Y1 = (S + corr + wd*px)/den
// emits split bf16 for the downstream MFMA graph-conv
__global__ void k_y1(const float* __restrict__ accb, const float* __restrict__ S,
                     const float* __restrict__ den, const int* __restrict__ seq,
                     const float* __restrict__ px,
                     unsigned short* __restrict__ yh, unsigned short* __restrict__ yl)
{
    size_t idx = (size_t)blockIdx.x * 256 + threadIdx.x;
    if (idx >= NPX) return;
    int r = (int)(idx / DHP);
    int b = r >> 11, i = r & (TT - 1);
    int d = (int)(idx - (size_t)r * DHP);
    float out = 0.f;
    if (i < seq[b])
        out = (S[b * DHP + d] + accb[idx] + diag_w() * px[idx]) / den[r];
    unsigned short hh = f2bf(out);
    yh[idx] = hh;
    yl[idx] = f2bf(out - bf2f(hh));
}

// ------------------------------------------------- disadj @ px via dual scan
// disadj[i,j] = r^|i-j|: full matvec = fwd + bwd first-order recursions with
// HALO=128 warmup (carry decay r^128 ~ 3.5e-21 — sub-fp32-eps at any px scale).
__global__ __launch_bounds__(256) void k_band(
    const float* __restrict__ px,
    unsigned short* __restrict__ yh, unsigned short* __restrict__ yl)
{
    __shared__ float Fs[CH][DHP];   // 73,728 B
    const int b = blockIdx.y;
    const int i0 = blockIdx.x * CH;
    const int tid = threadIdx.x;
    const bool hasB = (tid < DHP - 256);
    const float r = expf(-INV_E);
    const float* base = px + (size_t)b * TT * DHP;

    // forward scan with left halo
    {
        const int jlo = (i0 - HALO > 0) ? i0 - HALO : 0;
        float LA = 0.f, LB = 0.f;
        for (int j = jlo; j < i0 + CH; ++j) {
            const float* row = base + (size_t)j * DHP;
            LA = fmaf(r, LA, row[tid]);
            if (hasB) LB = fmaf(r, LB, row[256 + tid]);
            if (j >= i0) {
                Fs[j - i0][tid] = LA;
                if (hasB) Fs[j - i0][256 + tid] = LB;
            }
        }
    }
    __syncthreads();
    // backward scan with right halo; emit y = F + G - px
    {
        const int jhi = (i0 + CH - 1 + HALO < TT - 1) ? i0 + CH - 1 + HALO : TT - 1;
        float RA = 0.f, RB = 0.f;
        for (int j = jhi; j >= i0; --j) {
            const float* row = base + (size_t)j * DHP;
            float pa = row[tid];
            float pb = hasB ? row[256 + tid] : 0.f;
            RA = fmaf(r, RA, pa);
            if (hasB) RB = fmaf(r, RB, pb);
            if (j < i0 + CH) {
                size_t o = ((size_t)(b * TT + j)) * DHP + tid;
                float ya = Fs[j - i0][tid] + RA - pa;
                unsigned short hh = f2bf(ya);
                yh[o] = hh; yl[o] = f2bf(ya - bf2f(hh));
                if (hasB) {
                    float yb = Fs[j - i0][256 + tid] + RB - pb;
                    size_t ob = o + 256;
                    unsigned short h2 = f2bf(yb);
                    yh[ob] = h2; yl[ob] = f2bf(yb - bf2f(h2));
                }
            }
        }
    }
}

// ------------------------------------------------- frame_prob
__global__ __launch_bounds__(256) void k_frame(
    const float* __restrict__ x1, const float* __restrict__ x2f,
    const float* __restrict__ cls_w, const float* __restrict__ cls_b,
    float* __restrict__ dout)
{
    const int r = blockIdx.x * 4 + (threadIdx.x >> 6);
    const int lane = threadIdx.x & 63;
    float s = 0.f;
#pragma unroll
    for (int t = 0; t < 2; ++t) {
        int g = lane + t * 64;
        float cw1 = cls_w[g];
        if (g == 0) cw1 = -cw1;      // signs: only dim 0 negated
        s += x1[(size_t)r * DG_ + g] * cw1;
        s += x2f[(size_t)r * DG_ + g] * cls_w[DG_ + g];
    }
#pragma unroll
    for (int o = 32; o > 0; o >>= 1) s += __shfl_down(s, o, 64);
    if (lane == 0) dout[8 + r] = 2.0f + 2.0f * s + cls_b[0];
}

// ------------------------------------------------- top-k MIL (bitonic sort)
__global__ __launch_bounds__(1024) void k_clas(
    const int* __restrict__ seq, float* __restrict__ dout)
{
    __shared__ float s[TT];
    const int b = blockIdx.x, tid = threadIdx.x;
    const int nb = seq[b];
    for (int t = tid; t < TT; t += 1024)
        s[t] = (t < nb) ? dout[8 + b * TT + t] : -1e30f;
    __syncthreads();
    for (int k = 2; k <= TT; k <<= 1)
        for (int j = k >> 1; j > 0; j >>= 1) {
            for (int i = tid; i < TT; i += 1024) {
                int ixj = i ^ j;
                if (ixj > i) {
                    float a = s[i], c = s[ixj];
                    bool descBlk = ((i & k) == 0);
                    if (descBlk ? (a < c) : (a > c)) { s[i] = c; s[ixj] = a; }
                }
            }
            __syncthreads();
        }
    const int kk = nb / 16 + 1;
    float part = 0.f;
    for (int t = tid; t < kk; t += 1024) part += s[t];
#pragma unroll
    for (int o = 32; o > 0; o >>= 1) part += __shfl_down(part, o, 64);
    __shared__ float wred[16];
    if ((tid & 63) == 0) wred[tid >> 6] = part;
    __syncthreads();
    if (tid == 0) {
        float mil = 0.f;
#pragma unroll
        for (int t = 0; t < 16; ++t) mil += wred[t];
        mil /= (float)kk;
        dout[b] = 1.f / (1.f + expf(-mil));
    }
}

// ---------------------------------------------------------------- launch
extern "C" void kernel_launch(void* const* d_in, const int* in_sizes, int n_in,
                              void* d_out, int out_size, void* d_ws, size_t ws_size,
                              hipStream_t stream) {
    (void)in_sizes; (void)n_in; (void)out_size; (void)ws_size;
    const float* inputs = (const float*)d_in[0];
    const int*   seq    = (const int*)d_in[1];
    const float* w1     = (const float*)d_in[2];
    const float* b1     = (const float*)d_in[3];
    const float* w2     = (const float*)d_in[4];
    const float* b2     = (const float*)d_in[5];
    const float* gw1    = (const float*)d_in[6];
    const float* gw2    = (const float*)d_in[7];
    const float* cls_w  = (const float*)d_in[8];
    const float* cls_b  = (const float*)d_in[9];
    float* dout = (float*)d_out;
    float* ws = (float*)d_ws;

    // o_big region: Ah/Al (MLP1 input split) -> px + pxb + y2 + y1
    unsigned short* Ah = (unsigned short*)(ws + o_big);
    unsigned short* Al = Ah + (size_t)MTOT * DV_;
    float* px  = ws + o_big;
    unsigned short* pxb = (unsigned short*)(ws + o_big + 4718592);
    unsigned short* y2h = (unsigned short*)(ws + o_big + 7077888);
    unsigned short* y2l = y2h + NPX;
    unsigned short* y1h = (unsigned short*)(ws + o_big + 11796480);
    unsigned short* y1l = y1h + NPX;
    // o_c1 region: C1h/C1l -> accb + x1
    unsigned short* C1h = (unsigned short*)(ws + o_c1);
    unsigned short* C1l = C1h + (size_t)MTOT * D1_;
    float* accb = ws + o_c1;
    float* x1   = ws + o_c1 + 4718592;
    // o_c2 region: C2 -> x2f
    float* C2  = ws + o_c2;
    float* x2f = ws + o_c2;
    // weights
    unsigned short* wsS = (unsigned short*)(ws + o_w);
    unsigned short *W1h = wsS + sw_w1h, *W1l = wsS + sw_w1l;
    unsigned short *W2h = wsS + sw_w2h, *W2l = wsS + sw_w2l;
    unsigned short *g1h = wsS + sw_g1h, *g1l = wsS + sw_g1l;
    unsigned short *g2h = wsS + sw_g2h, *g2l = wsS + sw_g2l;
    float* S   = ws + o_S;
    float* den = ws + o_den;

    // init + splits
    k_init<<<MTOT / 256, 256, 0, stream>>>(den, seq, S);
    k_split_in<<<16384, 256, 0, stream>>>(inputs, Ah, Al);
    k_split_w<<<576, 256, 0, stream>>>(w1, w2, W1h, W1l, W2h, W2l);
    k_padgw_t<<<dim3(144, 2), 256, 0, stream>>>(gw1, gw2, g1h, g1l, g2h, g2l);

    // MLP1: LDS-staged split MFMA GEMM, XCD-swizzled
    gemm_mlp1<<<512, 256, 0, stream>>>(Ah, Al, W1h, W1l, b1, C1h, C1l);
    // MLP2
    gemm_mfma_nt<<<dim3(1, MTOT / 128), 256, 0, stream>>>(
        C1h, C1l, D1_, W2h, W2l, D1_, b2, C2, nullptr, nullptr, D2_, D1_);

    // expmap0 (px/pxb overwrite Ah region — Ah dead after MLP1)
    k_proj<<<MTOT, 256, 0, stream>>>(C2, inputs, px, pxb);

    // zero correction accumulator (overwrites C1 — dead after MLP2)
    k_zero<<<4096, 256, 0, stream>>>(accb, NPX);

    // valid column sums
    k_ssum<<<dim3(BB, TT / 32), 256, 0, stream>>>(px, seq, S);

    // Lorentz similarity via bf16 MFMA, upper triangle
    k_xy_mfma<<<dim3(TT / 128, TT / 128, BB), 256, 0, stream>>>(pxb, px, seq, den, accb);

    // Y1 = (S + corr + diag)/den -> split bf16
    k_y1<<<(int)(NPX / 256), 256, 0, stream>>>(accb, S, den, seq, px, y1h, y1l);

    // disadj @ px via dual scan -> split bf16
    k_band<<<dim3(TT / CH, BB), 256, 0, stream>>>(px, y2h, y2l);

    // merged graph-conv projections via MFMA
    gemm_gc<<<dim3(1, MTOT / 128, 2), 256, 0, stream>>>(
        y1h, y1l, y2h, y2l, g1h, g1l, g2h, g2l, x1, x2f);

    // frame_prob + MIL
    k_frame<<<MTOT / 4, 256, 0, stream>>>(x1, x2f, cls_w, cls_b, dout);
    k_clas<<<BB, 1024, 0, stream>>>(seq, dout);
}

// Round 11
// 407.871 us; speedup vs baseline: 1.4592x; 1.2280x over previous
//
#include <hip/hip_runtime.h>
#include <math.h>

// ---------------------------------------------------------------- constants
#define BB 8
#define TT 2048
#define DV_ 1024
#define DA_ 128
#define D1_ 512
#define D2_ 128
#define DH_ 257
#define DHP 288            // padded (zeros): divisible by 32 for MFMA K-chunks
#define DG_ 128
#define MTOT (BB*TT)       // 16384 rows
#define NPX ((size_t)MTOT*DHP)

#define NEGS 0.01f
#define INV_E 0.36787944117144233f
#define CH 64              // scan chunk rows
#define HALO 64            // r^64 ~ 6e-11 rel: truncation ~2e-6 abs on px~3e4 —
                           // far below the reference's own fp32 rounding
#define UB 8               // scan batch: 8 rows of loads issued together

#define RS 40              // MLP1 LDS row stride (hw): 80 B -> 20-bank step/row,
                           // worst aliasing 2-way (free, m136); 32 hw would be 8-way
#define BKC 32             // MLP1 K-chunk (halfwords)

// ---------------------------------------------------------------- workspace
static const size_t o_big = 0;                     // 16,777,216 f
static const size_t o_c1  = 16777216;              //  8,388,608 f
static const size_t o_c2  = o_c1 + 8388608;        //  2,097,152 f
static const size_t o_w   = o_c2 + 2097152;        //    663,552 f (split weights)
static const size_t o_S   = o_w + 663552;          //      2,304 f
static const size_t o_den = o_S + 2304;            //     16,384 f

// short offsets inside o_w
static const size_t sw_w1h = 0;          // 524,288
static const size_t sw_w1l = 524288;
static const size_t sw_w2h = 1048576;    // 65,536
static const size_t sw_w2l = 1114112;
static const size_t sw_g1h = 1179648;    // 36,864 ([128][288])
static const size_t sw_g1l = 1216512;
static const size_t sw_g2h = 1253376;
static const size_t sw_g2l = 1290240;

typedef __attribute__((ext_vector_type(8))) __bf16 bf16x8;
typedef __attribute__((ext_vector_type(8))) unsigned short us8;
typedef __attribute__((ext_vector_type(4))) float f32x4;

__device__ __forceinline__ float diag_w() {
    // identical fp32 ops to the generic path evaluated at xy == 1.0f
    float dd = logf(1.0f + sqrtf(1.0f*1.0f - 1.0f + 1e-7f));
    dd = fminf(fmaxf(dd, 1e-6f), 200.0f);
    float x2 = expf(-dd);
    return expf(x2) - 1.0f;
}

__device__ __forceinline__ unsigned short f2bf(float f) {
    unsigned int u = __float_as_uint(f);
    u += 0x7FFFu + ((u >> 16) & 1u);   // RNE
    return (unsigned short)(u >> 16);
}
__device__ __forceinline__ float bf2f(unsigned short h) {
    return __uint_as_float((unsigned int)h << 16);
}

// ---------------------------------------------------------------- utilities
__global__ void k_zero(float* __restrict__ p, size_t n) {
    size_t i = (size_t)blockIdx.x * 256 + threadIdx.x;
    size_t stride = (size_t)gridDim.x * 256;
    for (; i < n; i += stride) p[i] = 0.f;
}

// den init + S zero (merged)
__global__ void k_init(float* __restrict__ den, const int* __restrict__ seq,
                       float* __restrict__ S) {
    int r = blockIdx.x * 256 + threadIdx.x;   // 16384 total
    den[r] = (float)seq[r >> 11] + diag_w();
    if (r < BB * DHP) S[r] = 0.f;
}

// w1 + w2 fp32 -> (hi,lo) bf16 split in one launch
__global__ void k_split_w(const float* __restrict__ w1, const float* __restrict__ w2,
                          unsigned short* __restrict__ h1, unsigned short* __restrict__ l1,
                          unsigned short* __restrict__ h2, unsigned short* __restrict__ l2) {
    size_t i = ((size_t)blockIdx.x * 256 + threadIdx.x) * 4;
    const float* src; unsigned short *h, *l; size_t o;
    if (i < (size_t)D1_ * DV_) { src = w1; h = h1; l = l1; o = i; }
    else {
        o = i - (size_t)D1_ * DV_;
        if (o >= (size_t)D2_ * D1_) return;
        src = w2; h = h2; l = l2;
    }
    float4 v = *(const float4*)(src + o);
    ushort4 hv, lv;
    hv.x = f2bf(v.x); lv.x = f2bf(v.x - bf2f(hv.x));
    hv.y = f2bf(v.y); lv.y = f2bf(v.y - bf2f(hv.y));
    hv.z = f2bf(v.z); lv.z = f2bf(v.z - bf2f(hv.z));
    hv.w = f2bf(v.w); lv.w = f2bf(v.w - bf2f(hv.w));
    *(ushort4*)(h + o) = hv;
    *(ushort4*)(l + o) = lv;
}

// inputs[:, :, :1024] (row stride 1152) -> split [16384][1024]
__global__ void k_split_in(const float* __restrict__ inputs,
                           unsigned short* __restrict__ h,
                           unsigned short* __restrict__ l) {
    size_t i = ((size_t)blockIdx.x * 256 + threadIdx.x) * 4;
    if (i >= (size_t)MTOT * DV_) return;
    int r = (int)(i >> 10), c = (int)(i & 1023);
    float4 v = *(const float4*)(inputs + (size_t)r * 1152 + c);
    ushort4 hv, lv;
    hv.x = f2bf(v.x); lv.x = f2bf(v.x - bf2f(hv.x));
    hv.y = f2bf(v.y); lv.y = f2bf(v.y - bf2f(hv.y));
    hv.z = f2bf(v.z); lv.z = f2bf(v.z - bf2f(hv.z));
    hv.w = f2bf(v.w); lv.w = f2bf(v.w - bf2f(hv.w));
    *(ushort4*)(h + i) = hv;
    *(ushort4*)(l + i) = lv;
}

// gw1/gw2 [257][128] -> transposed, padded, split [128][288]; blockIdx.y picks
__global__ void k_padgw_t(const float* __restrict__ g1, const float* __restrict__ g2,
                          unsigned short* __restrict__ h1, unsigned short* __restrict__ l1,
                          unsigned short* __restrict__ h2, unsigned short* __restrict__ l2) {
    int i = blockIdx.x * 256 + threadIdx.x;   // DG*DHP = 36864
    if (i >= DG_ * DHP) return;
    const float* g = blockIdx.y ? g2 : g1;
    unsigned short* th = blockIdx.y ? h2 : h1;
    unsigned short* tl = blockIdx.y ? l2 : l1;
    int c = i / DHP, k = i - c * DHP;
    float v = (k < DH_) ? g[k * DG_ + c] : 0.f;
    unsigned short hh = f2bf(v);
    th[i] = hh;
    tl[i] = f2bf(v - bf2f(hh));
}

// ------------------------------------------------- MLP1: LDS-staged split GEMM
// LDS double-buffer (m93 pattern): coalesced 16B global loads -> ds_write_b128
// -> ds_read_b128 frags; 1 barrier/chunk. 80 KB LDS -> 2 blocks/CU.
// XCD swizzle keeps a 128-row A-panel's 4 col-tiles on one XCD (r8).
__global__ __launch_bounds__(256, 1) void gemm_mlp1(
    const unsigned short* __restrict__ Ah, const unsigned short* __restrict__ Al,
    const unsigned short* __restrict__ Bh, const unsigned short* __restrict__ Bl,
    const float* __restrict__ bias,
    unsigned short* __restrict__ Ch, unsigned short* __restrict__ Cl)
{
    __shared__ unsigned short sm[2][4][128 * RS];   // [buf][Ah,Al,Bh,Bl] = 80 KB
    const int ib = blockIdx.x;               // 512 blocks
    const int x = ib & 7, slot = ib >> 3;    // xcd lane, 64 slots
    const int cc = slot & 3, g = slot >> 2;  // col-tile, panel group
    const int row0 = (x + 8 * g) * 128, col0 = cc * 128;
    const int tid = threadIdx.x;
    const int wave = tid >> 6, lane = tid & 63;
    const int r0w = (wave >> 1) * 64, c0w = (wave & 1) * 64;   // block-local
    const int q = lane >> 4, m = lane & 15;
    // staging: thread covers rows srow and srow+64, 8-hw col slice
    const int srow = tid >> 2, scol = (tid & 3) << 3;
    const size_t gA0 = (size_t)(row0 + srow) * DV_ + scol;
    const size_t gA1 = (size_t)(row0 + srow + 64) * DV_ + scol;
    const size_t gB0 = (size_t)(col0 + srow) * DV_ + scol;
    const size_t gB1 = (size_t)(col0 + srow + 64) * DV_ + scol;
    const int s0 = srow * RS + scol, s1 = (srow + 64) * RS + scol;

    us8 rA0h, rA1h, rA0l, rA1l, rB0h, rB1h, rB0l, rB1l;
    rA0h = *(const us8*)(Ah + gA0); rA1h = *(const us8*)(Ah + gA1);
    rA0l = *(const us8*)(Al + gA0); rA1l = *(const us8*)(Al + gA1);
    rB0h = *(const us8*)(Bh + gB0); rB1h = *(const us8*)(Bh + gB1);
    rB0l = *(const us8*)(Bl + gB0); rB1l = *(const us8*)(Bl + gB1);
    *(us8*)&sm[0][0][s0] = rA0h; *(us8*)&sm[0][0][s1] = rA1h;
    *(us8*)&sm[0][1][s0] = rA0l; *(us8*)&sm[0][1][s1] = rA1l;
    *(us8*)&sm[0][2][s0] = rB0h; *(us8*)&sm[0][2][s1] = rB1h;
    *(us8*)&sm[0][3][s0] = rB0l; *(us8*)&sm[0][3][s1] = rB1l;
    __syncthreads();

    f32x4 acc[4][4];
#pragma unroll
    for (int a = 0; a < 4; ++a)
#pragma unroll
        for (int c = 0; c < 4; ++c) acc[a][c] = (f32x4){0.f, 0.f, 0.f, 0.f};

    const int NC = DV_ / BKC;   // 32 chunks
    for (int kc = 0; kc < NC; ++kc) {
        const int buf = kc & 1;
        const bool more = (kc + 1 < NC);
        if (more) {   // issue next chunk's global loads (latency hidden by MFMA)
            const size_t o = (size_t)(kc + 1) * BKC;
            rA0h = *(const us8*)(Ah + gA0 + o); rA1h = *(const us8*)(Ah + gA1 + o);
            rA0l = *(const us8*)(Al + gA0 + o); rA1l = *(const us8*)(Al + gA1 + o);
            rB0h = *(const us8*)(Bh + gB0 + o); rB1h = *(const us8*)(Bh + gB1 + o);
            rB0l = *(const us8*)(Bl + gB0 + o); rB1l = *(const us8*)(Bl + gB1 + o);
        }
        bf16x8 fah[4], fal[4], fbh[4], fbl[4];
#pragma unroll
        for (int t = 0; t < 4; ++t) {
            const int ra = (r0w + t*16 + m) * RS + q*8;
            const int rb = (c0w + t*16 + m) * RS + q*8;
            fah[t] = *(const bf16x8*)&sm[buf][0][ra];
            fal[t] = *(const bf16x8*)&sm[buf][1][ra];
            fbh[t] = *(const bf16x8*)&sm[buf][2][rb];
            fbl[t] = *(const bf16x8*)&sm[buf][3][rb];
        }
#pragma unroll
        for (int mi = 0; mi < 4; ++mi)
#pragma unroll
            for (int nj = 0; nj < 4; ++nj) {
                acc[mi][nj] = __builtin_amdgcn_mfma_f32_16x16x32_bf16(fah[mi], fbh[nj], acc[mi][nj], 0, 0, 0);
                acc[mi][nj] = __builtin_amdgcn_mfma_f32_16x16x32_bf16(fal[mi], fbh[nj], acc[mi][nj], 0, 0, 0);
                acc[mi][nj] = __builtin_amdgcn_mfma_f32_16x16x32_bf16(fah[mi], fbl[nj], acc[mi][nj], 0, 0, 0);
            }
        if (more) {
            const int nb = buf ^ 1;
            *(us8*)&sm[nb][0][s0] = rA0h; *(us8*)&sm[nb][0][s1] = rA1h;
            *(us8*)&sm[nb][1][s0] = rA0l; *(us8*)&sm[nb][1][s1] = rA1l;
            *(us8*)&sm[nb][2][s0] = rB0h; *(us8*)&sm[nb][2][s1] = rB1h;
            *(us8*)&sm[nb][3][s0] = rB0l; *(us8*)&sm[nb][3][s1] = rB1l;
        }
        __syncthreads();
    }
    float bj[4];
#pragma unroll
    for (int nj = 0; nj < 4; ++nj) bj[nj] = bias[col0 + c0w + nj*16 + m];
#pragma unroll
    for (int mi = 0; mi < 4; ++mi)
#pragma unroll
        for (int nj = 0; nj < 4; ++nj)
#pragma unroll
            for (int t = 0; t < 4; ++t) {
                int i = row0 + r0w + mi*16 + q*4 + t;
                int j = col0 + c0w + nj*16 + m;
                float v = acc[mi][nj][t] + bj[nj];
                v = (v >= 0.f) ? v : NEGS * v;
                size_t o = (size_t)i * D1_ + j;
                unsigned short hh = f2bf(v);
                Ch[o] = hh;
                Cl[o] = f2bf(v - bf2f(hh));
            }
}

// ------------------------------------------------- split-bf16x3 MFMA core
#define LOADK(S, k0) \
    _Pragma("unroll") \
    for (int t = 0; t < 4; ++t) { \
        size_t ao = (size_t)(r0 + t*16 + m) * lda + (k0) + q*8; \
        size_t bo = (size_t)(c0 + t*16 + m) * ldb + (k0) + q*8; \
        ah##S[t] = *(const bf16x8*)(Ah + ao); \
        al##S[t] = *(const bf16x8*)(Al + ao); \
        bh##S[t] = *(const bf16x8*)(Bh + bo); \
        bl##S[t] = *(const bf16x8*)(Bl + bo); \
    }
#define MFMAK(S) \
    _Pragma("unroll") \
    for (int mi = 0; mi < 4; ++mi) \
        _Pragma("unroll") \
        for (int nj = 0; nj < 4; ++nj) { \
            acc[mi][nj] = __builtin_amdgcn_mfma_f32_16x16x32_bf16(ah##S[mi], bh##S[nj], acc[mi][nj], 0, 0, 0); \
            acc[mi][nj] = __builtin_amdgcn_mfma_f32_16x16x32_bf16(al##S[mi], bh##S[nj], acc[mi][nj], 0, 0, 0); \
            acc[mi][nj] = __builtin_amdgcn_mfma_f32_16x16x32_bf16(ah##S[mi], bl##S[nj], acc[mi][nj], 0, 0, 0); \
        }

// ------------------------------------------------- generic split GEMM (NT)
// C = leaky(A*B^T + bias). Register double-buffer prefetch. (256,1): VGPR
// budget 512 (gfx950 default clamps to 64 -> spill).
__global__ __launch_bounds__(256, 1) void gemm_mfma_nt(
    const unsigned short* __restrict__ Ah, const unsigned short* __restrict__ Al, int lda,
    const unsigned short* __restrict__ Bh, const unsigned short* __restrict__ Bl, int ldb,
    const float* __restrict__ bias,
    float* __restrict__ Cf, unsigned short* __restrict__ Ch, unsigned short* __restrict__ Cl,
    int N, int K)
{
    const int row0 = blockIdx.y * 128, col0 = blockIdx.x * 128;
    const int wave = threadIdx.x >> 6, lane = threadIdx.x & 63;
    const int r0 = row0 + (wave >> 1) * 64, c0 = col0 + (wave & 1) * 64;
    const int q = lane >> 4, m = lane & 15;
    f32x4 acc[4][4];
#pragma unroll
    for (int a = 0; a < 4; ++a)
#pragma unroll
        for (int c = 0; c < 4; ++c) acc[a][c] = (f32x4){0.f, 0.f, 0.f, 0.f};
    bf16x8 ah0[4], al0[4], bh0[4], bl0[4];
    bf16x8 ah1[4], al1[4], bh1[4], bl1[4];
    LOADK(0, 0)
    int k0 = 0;
    for (; k0 + 64 <= K; k0 += 64) {
        LOADK(1, k0 + 32)
        MFMAK(0)
        if (k0 + 64 < K) { LOADK(0, k0 + 64) }
        MFMAK(1)
    }
    if (k0 < K) { MFMAK(0) }   // odd tail chunk (K=288)
    float bj[4];
#pragma unroll
    for (int nj = 0; nj < 4; ++nj)
        bj[nj] = bias ? bias[c0 + nj*16 + m] : 0.f;
#pragma unroll
    for (int mi = 0; mi < 4; ++mi)
#pragma unroll
        for (int nj = 0; nj < 4; ++nj)
#pragma unroll
            for (int t = 0; t < 4; ++t) {
                int i = r0 + mi*16 + q*4 + t;
                int j = c0 + nj*16 + m;
                float v = acc[mi][nj][t] + bj[nj];
                v = (v >= 0.f) ? v : NEGS * v;
                size_t o = (size_t)i * N + j;
                if (Cf) Cf[o] = v;
                if (Ch) {
                    unsigned short hh = f2bf(v);
                    Ch[o] = hh;
                    Cl[o] = f2bf(v - bf2f(hh));
                }
            }
}

// ------------------------------------------------- merged graph-conv GEMMs
// x1 = leaky(y1 @ g1), x2 = leaky(y2 @ g2) in one launch (blockIdx.z picks).
__global__ __launch_bounds__(256, 1) void gemm_gc(
    const unsigned short* __restrict__ A1h, const unsigned short* __restrict__ A1l,
    const unsigned short* __restrict__ A2h, const unsigned short* __restrict__ A2l,
    const unsigned short* __restrict__ G1h, const unsigned short* __restrict__ G1l,
    const unsigned short* __restrict__ G2h, const unsigned short* __restrict__ G2l,
    float* __restrict__ X1, float* __restrict__ X2)
{
    const int z = blockIdx.z;
    const unsigned short* Ah = z ? A2h : A1h;
    const unsigned short* Al = z ? A2l : A1l;
    const unsigned short* Bh = z ? G2h : G1h;
    const unsigned short* Bl = z ? G2l : G1l;
    float* Cf = z ? X2 : X1;
    const int lda = DHP, ldb = DHP;
    const int row0 = blockIdx.y * 128, col0 = 0;
    const int wave = threadIdx.x >> 6, lane = threadIdx.x & 63;
    const int r0 = row0 + (wave >> 1) * 64, c0 = col0 + (wave & 1) * 64;
    const int q = lane >> 4, m = lane & 15;
    f32x4 acc[4][4];
#pragma unroll
    for (int a = 0; a < 4; ++a)
#pragma unroll
        for (int c = 0; c < 4; ++c) acc[a][c] = (f32x4){0.f, 0.f, 0.f, 0.f};
    bf16x8 ah0[4], al0[4], bh0[4], bl0[4];
    bf16x8 ah1[4], al1[4], bh1[4], bl1[4];
    LOADK(0, 0)
    int k0 = 0;
    for (; k0 + 64 <= DHP; k0 += 64) {
        LOADK(1, k0 + 32)
        MFMAK(0)
        if (k0 + 64 < DHP) { LOADK(0, k0 + 64) }
        MFMAK(1)
    }
    if (k0 < DHP) { MFMAK(0) }   // K=288 tail
#pragma unroll
    for (int mi = 0; mi < 4; ++mi)
#pragma unroll
        for (int nj = 0; nj < 4; ++nj)
#pragma unroll
            for (int t = 0; t < 4; ++t) {
                int i = r0 + mi*16 + q*4 + t;
                int j = c0 + nj*16 + m;
                float v = acc[mi][nj][t];
                v = (v >= 0.f) ? v : NEGS * v;
                Cf[(size_t)i * DG_ + j] = v;
            }
}

// ------------------------------------------------- xy via bf16 MFMA (upper tri)
// Only observable effect: which pairs pass x2>0.8. Off-diag xy huge vs band
// [1,1.026]; bf16 error negligible -> classification identical to fp32/f64.
#define XLOAD(S, k0) \
    _Pragma("unroll") \
    for (int t = 0; t < 4; ++t) { \
        af##S[t] = *(const bf16x8*)(base + (size_t)(r0 + t*16 + m) * DHP + (k0) + q*8); \
        bf##S[t] = *(const bf16x8*)(base + (size_t)(c0 + t*16 + m) * DHP + (k0) + q*8); \
    }
#define XMFMA(S) \
    _Pragma("unroll") \
    for (int mi = 0; mi < 4; ++mi) \
        _Pragma("unroll") \
        for (int nj = 0; nj < 4; ++nj) \
            acc[mi][nj] = __builtin_amdgcn_mfma_f32_16x16x32_bf16(af##S[mi], bf##S[nj], acc[mi][nj], 0, 0, 0);

__global__ __launch_bounds__(256, 1) void k_xy_mfma(
    const unsigned short* __restrict__ pxb, const float* __restrict__ px,
    const int* __restrict__ seq, float* __restrict__ den, float* __restrict__ accb)
{
    const int b = blockIdx.z;
    const int bx = blockIdx.x, by = blockIdx.y;
    if (bx < by) return;
    const int nb = seq[b];
    const int row0 = by * 128, col0 = bx * 128;
    if (row0 >= nb || col0 >= nb) return;
    const int wave = threadIdx.x >> 6, lane = threadIdx.x & 63;
    const int r0 = row0 + (wave >> 1) * 64, c0 = col0 + (wave & 1) * 64;
    if (c0 + 63 < r0 || r0 >= nb || c0 >= nb) return;   // wave-uniform exits
    const unsigned short* base = pxb + (size_t)b * TT * DHP;
    const int q = lane >> 4, m = lane & 15;
    f32x4 acc[4][4];
#pragma unroll
    for (int a = 0; a < 4; ++a)
#pragma unroll
        for (int c = 0; c < 4; ++c) acc[a][c] = (f32x4){0.f, 0.f, 0.f, 0.f};
    bf16x8 af0[4], bf0[4], af1[4], bf1[4];
    XLOAD(0, 0)
    int k0 = 0;
    for (; k0 + 64 <= DHP; k0 += 64) {
        XLOAD(1, k0 + 32)
        XMFMA(0)
        if (k0 + 64 < DHP) { XLOAD(0, k0 + 64) }
        XMFMA(1)
    }
    if (k0 < DHP) { XMFMA(0) }
    const float* b32 = px + (size_t)b * TT * DHP;
    float cj[4], ci[4][4];
#pragma unroll
    for (int nj = 0; nj < 4; ++nj) cj[nj] = b32[(size_t)(c0 + nj*16 + m) * DHP];
#pragma unroll
    for (int mi = 0; mi < 4; ++mi)
#pragma unroll
        for (int t = 0; t < 4; ++t) ci[mi][t] = b32[(size_t)(r0 + mi*16 + q*4 + t) * DHP];
#pragma unroll
    for (int mi = 0; mi < 4; ++mi)
#pragma unroll
        for (int nj = 0; nj < 4; ++nj)
#pragma unroll
            for (int t = 0; t < 4; ++t) {
                int i = r0 + mi*16 + q*4 + t;
                int j = c0 + nj*16 + m;
                if (i < j && j < nb) {
                    float xyv = 2.f * ci[mi][t] * cj[nj] - acc[mi][nj][t];
                    float xym = fmaxf(xyv, 1.0f);
                    // xym >= 1.026 => x2 <= 0.798 < 0.8: no correction
                    if (xym < 1.026f) {
                        float dd = logf(xym + sqrtf(xym * xym - 1.0f + 1e-7f));
                        dd = fminf(fmaxf(dd, 1e-6f), 200.0f);
                        float x2v = expf(-dd);
                        if (x2v > 0.8f) {
                            float w = expf(x2v) - 1.0f;
                            atomicAdd(&den[b * TT + i], w);
                            atomicAdd(&den[b * TT + j], w);
                            const float* pi = b32 + (size_t)i * DHP;
                            const float* pj = b32 + (size_t)j * DHP;
                            float* ai = accb + ((size_t)(b * TT + i)) * DHP;
                            float* aj = accb + ((size_t)(b * TT + j)) * DHP;
                            for (int d = 0; d < DHP; ++d) {
                                atomicAdd(&ai[d], w * pj[d]);
                                atomicAdd(&aj[d], w * pi[d]);
                            }
                        }
                    }
                }
            }
}

// ------------------------------------------------- expmap0 (px fp32 + bf16)
__global__ __launch_bounds__(256) void k_proj(
    const float* __restrict__ C2, const float* __restrict__ inputs,
    float* __restrict__ px, unsigned short* __restrict__ pxb)
{
    const int r = blockIdx.x;
    const int tid = threadIdx.x;
    float v = (tid < 128) ? C2[(size_t)r * 128 + tid]
                          : inputs[(size_t)r * 1152 + 1024 + (tid - 128)];
    float sq = v * v;
#pragma unroll
    for (int o = 32; o > 0; o >>= 1) sq += __shfl_down(sq, o, 64);
    __shared__ float wred[4];
    __shared__ float cs[2];
    if ((tid & 63) == 0) wred[tid >> 6] = sq;
    __syncthreads();
    if (tid == 0) {
        float n2 = fmaxf(wred[0] + wred[1] + wred[2] + wred[3], 1e-12f);
        float n = sqrtf(n2);
        cs[0] = coshf(n);
        cs[1] = sinhf(n) / n;
    }
    __syncthreads();
    float sv = cs[1] * v;
    px[(size_t)r * DHP + 1 + tid] = sv;
    pxb[(size_t)r * DHP + 1 + tid] = f2bf(sv);
    if (tid == 0) {
        px[(size_t)r * DHP] = cs[0];
        pxb[(size_t)r * DHP] = f2bf(cs[0]);
    }
    if (tid < DHP - DH_) {   // 31 pad zeros
        px[(size_t)r * DHP + DH_ + tid] = 0.f;
        pxb[(size_t)r * DHP + DH_ + tid] = 0;
    }
}

// ------------------------------------------------- per-batch valid column sum
__global__ __launch_bounds__(256) void k_ssum(
    const float* __restrict__ px, const int* __restrict__ seq,
    float* __restrict__ S)
{
    const int b = blockIdx.x, chunk = blockIdx.y, tid = threadIdx.x;
    const int nb = seq[b];
    const int j0 = chunk * 32;
    const int j1 = (j0 + 32 < nb) ? j0 + 32 : nb;
    float a0 = 0.f, a1 = 0.f;
    const bool hasB = (tid < DHP - 256);
    for (int j = j0; j < j1; ++j) {
        const float* row = px + ((size_t)(b * TT + j)) * DHP;
        a0 += row[tid];
        if (hasB) a1 += row[256 + tid];
    }
    if (j1 > j0) {
        atomicAdd(&S[b * DHP + tid], a0);
        if (hasB) atomicAdd(&S[b * DHP + 256 + tid], a1);
    }
}

// ------------------------------------------------- Y1 = (S + corr + wd*px)/den
// emits split bf16 for the downstream MFMA graph-conv
__global__ void k_y1(const float* __restrict__ accb, const float* __restrict__ S,
                     const float* __restrict__ den, const int* __restrict__ seq,
                     const float* __restrict__ px,
                     unsigned short* __restrict__ yh, unsigned short* __restrict__ yl)
{
    size_t idx = (size_t)blockIdx.x * 256 + threadIdx.x;
    if (idx >= NPX) return;
    int r = (int)(idx / DHP);
    int b = r >> 11, i = r & (TT - 1);
    int d = (int)(idx - (size_t)r * DHP);
    float out = 0.f;
    if (i < seq[b])
        out = (S[b * DHP + d] + accb[idx] + diag_w() * px[idx]) / den[r];
    unsigned short hh = f2bf(out);
    yh[idx] = hh;
    yl[idx] = f2bf(out - bf2f(hh));
}

// ------------------------------------------------- disadj @ px via dual scan
// disadj[i,j] = r^|i-j|: full matvec = fwd + bwd first-order recursions.
// r10: one load per serial iter = full HBM latency each (~760 cyc/iter,
// VALUBusy 3.7%). Fix: batch UB=8 rows of loads (16 independent loads issued
// together, one vmcnt drain), then run the 8-step fmaf chain on registers.
// HALO 128->64: r^64 ~ 6e-11 rel — truncation ~2e-6 abs, far below fp32
// rounding of the reference's dense sum. All phase lengths divide by UB.
__global__ __launch_bounds__(256) void k_band(
    const float* __restrict__ px,
    unsigned short* __restrict__ yh, unsigned short* __restrict__ yl)
{
    __shared__ float Fs[CH][DHP];   // 73,728 B
    const int b = blockIdx.y;
    const int i0 = blockIdx.x * CH;
    const int tid = threadIdx.x;
    const bool hasB = (tid < DHP - 256);
    const float r = expf(-INV_E);
    const float* base = px + (size_t)b * TT * DHP;

    // forward scan with left halo (batched)
    {
        const int jlo = (i0 - HALO > 0) ? i0 - HALO : 0;   // length mult of UB
        float LA = 0.f, LB = 0.f;
        for (int j = jlo; j < i0 + CH; j += UB) {
            float va[UB], vb[UB];
#pragma unroll
            for (int u = 0; u < UB; ++u) {
                const float* row = base + (size_t)(j + u) * DHP;
                va[u] = row[tid];
                vb[u] = hasB ? row[256 + tid] : 0.f;
            }
#pragma unroll
            for (int u = 0; u < UB; ++u) {
                LA = fmaf(r, LA, va[u]);
                LB = fmaf(r, LB, vb[u]);
                const int jj = j + u;
                if (jj >= i0) {
                    Fs[jj - i0][tid] = LA;
                    if (hasB) Fs[jj - i0][256 + tid] = LB;
                }
            }
        }
    }
    __syncthreads();
    // backward: halo warmup (batched), then chunk phase with emit
    {
        const int jhi = (i0 + CH - 1 + HALO < TT - 1) ? i0 + CH - 1 + HALO : TT - 1;
        float RA = 0.f, RB = 0.f;
        int j = jhi;
        for (; j >= i0 + CH; j -= UB) {    // warmup length mult of UB
            float va[UB], vb[UB];
#pragma unroll
            for (int u = 0; u < UB; ++u) {
                const float* row = base + (size_t)(j - u) * DHP;
                va[u] = row[tid];
                vb[u] = hasB ? row[256 + tid] : 0.f;
            }
#pragma unroll
            for (int u = 0; u < UB; ++u) {
                RA = fmaf(r, RA, va[u]);
                RB = fmaf(r, RB, vb[u]);
            }
        }
        for (; j >= i0; j -= UB) {         // chunk phase: emit every row
            float va[UB], vb[UB];
#pragma unroll
            for (int u = 0; u < UB; ++u) {
                const float* row = base + (size_t)(j - u) * DHP;
                va[u] = row[tid];
                vb[u] = hasB ? row[256 + tid] : 0.f;
            }
#pragma unroll
            for (int u = 0; u < UB; ++u) {
                const int jj = j - u;
                RA = fmaf(r, RA, va[u]);
                RB = fmaf(r, RB, vb[u]);
                size_t o = ((size_t)(b * TT + jj)) * DHP + tid;
                float ya = Fs[jj - i0][tid] + RA - va[u];
                unsigned short hh = f2bf(ya);
                yh[o] = hh; yl[o] = f2bf(ya - bf2f(hh));
                if (hasB) {
                    float yb = Fs[jj - i0][256 + tid] + RB - vb[u];
                    size_t ob = o + 256;
                    unsigned short h2 = f2bf(yb);
                    yh[ob] = h2; yl[ob] = f2bf(yb - bf2f(h2));
                }
            }
        }
    }
}

// ------------------------------------------------- frame_prob
__global__ __launch_bounds__(256) void k_frame(
    const float* __restrict__ x1, const float* __restrict__ x2f,
    const float* __restrict__ cls_w, const float* __restrict__ cls_b,
    float* __restrict__ dout)
{
    const int r = blockIdx.x * 4 + (threadIdx.x >> 6);
    const int lane = threadIdx.x & 63;
    float s = 0.f;
#pragma unroll
    for (int t = 0; t < 2; ++t) {
        int g = lane + t * 64;
        float cw1 = cls_w[g];
        if (g == 0) cw1 = -cw1;      // signs: only dim 0 negated
        s += x1[(size_t)r * DG_ + g] * cw1;
        s += x2f[(size_t)r * DG_ + g] * cls_w[DG_ + g];
    }
#pragma unroll
    for (int o = 32; o > 0; o >>= 1) s += __shfl_down(s, o, 64);
    if (lane == 0) dout[8 + r] = 2.0f + 2.0f * s + cls_b[0];
}

// ------------------------------------------------- top-k MIL (bitonic sort)
__global__ __launch_bounds__(1024) void k_clas(
    const int* __restrict__ seq, float* __restrict__ dout)
{
    __shared__ float s[TT];
    const int b = blockIdx.x, tid = threadIdx.x;
    const int nb = seq[b];
    for (int t = tid; t < TT; t += 1024)
        s[t] = (t < nb) ? dout[8 + b * TT + t] : -1e30f;
    __syncthreads();
    for (int k = 2; k <= TT; k <<= 1)
        for (int j = k >> 1; j > 0; j >>= 1) {
            for (int i = tid; i < TT; i += 1024) {
                int ixj = i ^ j;
                if (ixj > i) {
                    float a = s[i], c = s[ixj];
                    bool descBlk = ((i & k) == 0);
                    if (descBlk ? (a < c) : (a > c)) { s[i] = c; s[ixj] = a; }
                }
            }
            __syncthreads();
        }
    const int kk = nb / 16 + 1;
    float part = 0.f;
    for (int t = tid; t < kk; t += 1024) part += s[t];
#pragma unroll
    for (int o = 32; o > 0; o >>= 1) part += __shfl_down(part, o, 64);
    __shared__ float wred[16];
    if ((tid & 63) == 0) wred[tid >> 6] = part;
    __syncthreads();
    if (tid == 0) {
        float mil = 0.f;
#pragma unroll
        for (int t = 0; t < 16; ++t) mil += wred[t];
        mil /= (float)kk;
        dout[b] = 1.f / (1.f + expf(-mil));
    }
}

// ---------------------------------------------------------------- launch
extern "C" void kernel_launch(void* const* d_in, const int* in_sizes, int n_in,
                              void* d_out, int out_size, void* d_ws, size_t ws_size,
                              hipStream_t stream) {
    (void)in_sizes; (void)n_in; (void)out_size; (void)ws_size;
    const float* inputs = (const float*)d_in[0];
    const int*   seq    = (const int*)d_in[1];
    const float* w1     = (const float*)d_in[2];
    const float* b1     = (const float*)d_in[3];
    const float* w2     = (const float*)d_in[4];
    const float* b2     = (const float*)d_in[5];
    const float* gw1    = (const float*)d_in[6];
    const float* gw2    = (const float*)d_in[7];
    const float* cls_w  = (const float*)d_in[8];
    const float* cls_b  = (const float*)d_in[9];
    float* dout = (float*)d_out;
    float* ws = (float*)d_ws;

    // o_big region: Ah/Al (MLP1 input split) -> px + pxb + y2 + y1
    unsigned short* Ah = (unsigned short*)(ws + o_big);
    unsigned short* Al = Ah + (size_t)MTOT * DV_;
    float* px  = ws + o_big;
    unsigned short* pxb = (unsigned short*)(ws + o_big + 4718592);
    unsigned short* y2h = (unsigned short*)(ws + o_big + 7077888);
    unsigned short* y2l = y2h + NPX;
    unsigned short* y1h = (unsigned short*)(ws + o_big + 11796480);
    unsigned short* y1l = y1h + NPX;
    // o_c1 region: C1h/C1l -> accb + x1
    unsigned short* C1h = (unsigned short*)(ws + o_c1);
    unsigned short* C1l = C1h + (size_t)MTOT * D1_;
    float* accb = ws + o_c1;
    float* x1   = ws + o_c1 + 4718592;
    // o_c2 region: C2 -> x2f
    float* C2  = ws + o_c2;
    float* x2f = ws + o_c2;
    // weights
    unsigned short* wsS = (unsigned short*)(ws + o_w);
    unsigned short *W1h = wsS + sw_w1h, *W1l = wsS + sw_w1l;
    unsigned short *W2h = wsS + sw_w2h, *W2l = wsS + sw_w2l;
    unsigned short *g1h = wsS + sw_g1h, *g1l = wsS + sw_g1l;
    unsigned short *g2h = wsS + sw_g2h, *g2l = wsS + sw_g2l;
    float* S   = ws + o_S;
    float* den = ws + o_den;

    // init + splits
    k_init<<<MTOT / 256, 256, 0, stream>>>(den, seq, S);
    k_split_in<<<16384, 256, 0, stream>>>(inputs, Ah, Al);
    k_split_w<<<576, 256, 0, stream>>>(w1, w2, W1h, W1l, W2h, W2l);
    k_padgw_t<<<dim3(144, 2), 256, 0, stream>>>(gw1, gw2, g1h, g1l, g2h, g2l);

    // MLP1: LDS-staged split MFMA GEMM, XCD-swizzled
    gemm_mlp1<<<512, 256, 0, stream>>>(Ah, Al, W1h, W1l, b1, C1h, C1l);
    // MLP2
    gemm_mfma_nt<<<dim3(1, MTOT / 128), 256, 0, stream>>>(
        C1h, C1l, D1_, W2h, W2l, D1_, b2, C2, nullptr, nullptr, D2_, D1_);

    // expmap0 (px/pxb overwrite Ah region — Ah dead after MLP1)
    k_proj<<<MTOT, 256, 0, stream>>>(C2, inputs, px, pxb);

    // zero correction accumulator (overwrites C1 — dead after MLP2)
    k_zero<<<4096, 256, 0, stream>>>(accb, NPX);

    // valid column sums
    k_ssum<<<dim3(BB, TT / 32), 256, 0, stream>>>(px, seq, S);

    // Lorentz similarity via bf16 MFMA, upper triangle
    k_xy_mfma<<<dim3(TT / 128, TT / 128, BB), 256, 0, stream>>>(pxb, px, seq, den, accb);

    // Y1 = (S + corr + diag)/den -> split bf16
    k_y1<<<(int)(NPX / 256), 256, 0, stream>>>(accb, S, den, seq, px, y1h, y1l);

    // disadj @ px via batched dual scan -> split bf16
    k_band<<<dim3(TT / CH, BB), 256, 0, stream>>>(px, y2h, y2l);

    // merged graph-conv projections via MFMA
    gemm_gc<<<dim3(1, MTOT / 128, 2), 256, 0, stream>>>(
        y1h, y1l, y2h, y2l, g1h, g1l, g2h, g2l, x1, x2f);

    // frame_prob + MIL
    k_frame<<<MTOT / 4, 256, 0, stream>>>(x1, x2f, cls_w, cls_b, dout);
    k_clas<<<BB, 1024, 0, stream>>>(seq, dout);
}